// Round 2
// baseline (4983.485 us; speedup 1.0000x reference)
//
#include <hip/hip_runtime.h>
#include <math.h>

#pragma clang fp contract(off)

#define BS 8
#define CCH 20
#define IMH 480
#define IMW 640
#define HW (IMH*IMW)
#define VRX 100
#define NZ 88
#define NSEMC 16
#define CROP0 124
#define CROPN 232
#define NROTC 18

// -------------------- pose / theta params --------------------
__global__ void pose_kernel(const float* __restrict__ pose_obs,
                            const float* __restrict__ poses_last,
                            float* __restrict__ outp1, float* __restrict__ outp2,
                            float* __restrict__ posebuf) {
#pragma clang fp contract(off)
  int b = threadIdx.x;
  if (b >= BS) return;
  const float DEGF = (float)57.29577951308232;
  float th = poses_last[b*3+2] / DEGF;
  float sn = sinf(th), cs = cosf(th);
  float ny = poses_last[b*3+1] + pose_obs[b*3+0]*sn + pose_obs[b*3+1]*cs;
  float nx = poses_last[b*3+0] + pose_obs[b*3+0]*cs - pose_obs[b*3+1]*sn;
  float nt = poses_last[b*3+2] + pose_obs[b*3+2]*DEGF;
  nt = fmodf(nt - 180.0f, 360.0f) + 180.0f;
  nt = fmodf(nt + 180.0f, 360.0f) - 180.0f;
  outp1[b*3+0] = nx; outp1[b*3+1] = ny; outp1[b*3+2] = nt;
  outp2[b*3+0] = nx; outp2[b*3+1] = ny; outp2[b*3+2] = nt;
  float t = (90.0f - nt) * (float)M_PI / 180.0f;
  float* pb = posebuf + b*8;
  pb[0] = cosf(t);
  pb[1] = sinf(t);
  pb[2] = -((nx*100.0f/5.0f - 240.0f)/240.0f);   // stx
  pb[3] = -((ny*100.0f/5.0f - 240.0f)/240.0f);   // sty
}

// -------------------- bottom-row depth mask --------------------
__global__ void mask_kernel(const float* __restrict__ obs, float* __restrict__ posebuf,
                            float MINVF) {
#pragma clang fp contract(off)
  int b = blockIdx.x;
  int t = threadIdx.x;
  const float* row = obs + (size_t)b*CCH*HW + 3*(size_t)HW + 479*IMW;
  int cnt = 0;
  for (int col = t; col < IMW; col += 256) {
    float d = row[col];
    float re = (d < 3000.0f) ? d : MINVF;
    float v = re - MINVF;
    v = v - 60.0f;
    if (v > 0.0f) cnt++;
  }
  __shared__ int sh[256];
  sh[t] = cnt;
  __syncthreads();
  for (int s = 128; s > 0; s >>= 1) {
    if (t < s) sh[t] += sh[t + s];
    __syncthreads();
  }
  if (t == 0) posebuf[b*8+4] = (sh[0] > 160) ? 1.0f : 0.0f;
}

// -------------------- fused 8-corner scatter for one batch --------------------
// S0t layout: [tz 88][ty 100][tx 100][k 8]
// Ssemt layout: [tz-23 10][ty*100+tx][k 8][ch 16]
__global__ void scatter2_kernel(const float* __restrict__ obs,
                                const float* __restrict__ agent_h,
                                float* __restrict__ S0t, float* __restrict__ Ssemt,
                                float FOCALF, int b) {
#pragma clang fp contract(off)
  int tid = blockIdx.x*256 + threadIdx.x;
  if (tid >= HW) return;
  int r = tid / IMW;
  int col = tid - r*IMW;
  const float* obsb = obs + (size_t)b*CCH*HW;
  float Yd = obsb[3*(size_t)HW + tid];
  float ah100 = agent_h[b] * 100.0f;
  // exact reference f32 sequence (contraction off)
  float X = ((float)col - 319.5f) * Yd / FOCALF;
  X = X + 250.0f;
  float Z = ((float)(479 - r) - 239.5f) * Yd / FOCALF;
  Z = Z + ah100;
  float Xc = (X/5.0f - 50.0f)/100.0f*2.0f;
  float Yc = (Yd/5.0f - 50.0f)/100.0f*2.0f;
  float Zc = (Z/5.0f - 28.0f)/88.0f*2.0f;
  float pos0 = Xc*50.0f + 50.0f;
  float pos1 = Yc*50.0f + 50.0f;
  float pos2 = Zc*44.0f + 44.0f;
  float f0 = floorf(pos0), f1 = floorf(pos1), f2 = floorf(pos2);
  float px[2] = {f0, f0 + 1.0f};
  float py[2] = {f1, f1 + 1.0f};
  float pz[2] = {f2, f2 + 1.0f};
  float wx[2], wy[2], wz[2];
  bool  vx[2], vy[2], vz[2];
#pragma unroll
  for (int i = 0; i < 2; i++) {
    wx[i] = 1.0f - fabsf(pos0 - px[i]); vx[i] = (px[i] > 0.0f) && (px[i] < 100.0f);
    wy[i] = 1.0f - fabsf(pos1 - py[i]); vy[i] = (py[i] > 0.0f) && (py[i] < 100.0f);
    wz[i] = 1.0f - fabsf(pos2 - pz[i]); vz[i] = (pz[i] > 0.0f) && (pz[i] < 88.0f);
  }
  int xi = (int)f0, yi = (int)f1, zi = (int)f2;

  // preload sem channel values if any corner can land in [23,33)
  float v[NSEMC];
  bool needSem = (zi >= 22) && (zi <= 32) && (vz[0] || vz[1]) &&
                 (vx[0] || vx[1]) && (vy[0] || vy[1]);
  if (needSem) {
#pragma unroll
    for (int ch = 0; ch < NSEMC; ch++)
      v[ch] = obsb[(size_t)(4 + ch)*HW + tid];
  }

#pragma unroll
  for (int k = 0; k < 8; k++) {
    int ix = (k >> 2) & 1, iy = (k >> 1) & 1, iz = k & 1;
    if (!(vx[ix] && vy[iy] && vz[iz])) continue;
    float w = wx[ix]*wy[iy];
    w = w*wz[iz];
    if (w == 0.0f) continue;
    int tz = zi + iz, ty = yi + iy, tx = xi + ix;
    atomicAdd(&S0t[(size_t)((tz*VRX + ty)*VRX + tx)*8 + k], w);
    if (needSem && tz >= 23 && tz < 33) {
      float* dp = &Ssemt[((size_t)(tz - 23)*10000 + ty*VRX + tx)*128 + k*16];
#pragma unroll
      for (int ch = 0; ch < NSEMC; ch++)
        atomicAdd(dp + ch, v[ch]*w);
    }
  }
}

// -------------------- fold: round per corner, project, zero-restore --------------------
// part 1: tid in [0, 880000): (cz, cell) -> S0t
// part 2: tid in [880000, 980000): (czr, cell) -> Ssemt
__global__ void fold2_kernel(float* __restrict__ S0t, float* __restrict__ Ssemt,
                             float* __restrict__ ahp0, float* __restrict__ all0,
                             float* __restrict__ around0, float* __restrict__ mid0,
                             float* __restrict__ semacc, int b) {
  int tid = blockIdx.x*256 + threadIdx.x;
  if (tid < 880000) {
    int cz = tid / 10000;
    int cell = tid - cz*10000;
    float4* p = (float4*)&S0t[(size_t)tid*8];
    float4 a = p[0], c = p[1];
    bool nz = (a.x!=0.f)|(a.y!=0.f)|(a.z!=0.f)|(a.w!=0.f)|
              (c.x!=0.f)|(c.y!=0.f)|(c.z!=0.f)|(c.w!=0.f);
    if (!nz) return;
    float s = rintf(a.x)+rintf(a.y)+rintf(a.z)+rintf(a.w)
            + rintf(c.x)+rintf(c.y)+rintf(c.z)+rintf(c.w);
    p[0] = float4{0.f,0.f,0.f,0.f};
    p[1] = float4{0.f,0.f,0.f,0.f};
    if (s != 0.0f) {
      int o = b*10000 + cell;
      atomicAdd(&all0[o], s);
      if (cz < 23) {
        atomicAdd(&around0[o], s);
        if (cz >= 9) atomicAdd(&mid0[o], s);
      } else if (cz < 33) {
        atomicAdd(&ahp0[o], s);
      }
    }
  } else if (tid < 980000) {
    int i = tid - 880000;
    int cell = i % 10000;
    float4* p = (float4*)&Ssemt[(size_t)i*128];
    float sem[NSEMC];
#pragma unroll
    for (int ch = 0; ch < NSEMC; ch++) sem[ch] = 0.0f;
    bool nz = false;
#pragma unroll
    for (int k = 0; k < 8; k++) {
#pragma unroll
      for (int q = 0; q < 4; q++) {
        float4 a = p[k*4 + q];
        nz = nz | (a.x!=0.f) | (a.y!=0.f) | (a.z!=0.f) | (a.w!=0.f);
        sem[q*4+0] += rintf(a.x);
        sem[q*4+1] += rintf(a.y);
        sem[q*4+2] += rintf(a.z);
        sem[q*4+3] += rintf(a.w);
      }
    }
    if (!nz) return;
#pragma unroll
    for (int k = 0; k < 32; k++) p[k] = float4{0.f,0.f,0.f,0.f};
#pragma unroll
    for (int ch = 0; ch < NSEMC; ch++) {
      if (sem[ch] != 0.0f)
        atomicAdd(&semacc[((size_t)b*NSEMC + ch)*10000 + cell], sem[ch]);
    }
  }
}

// -------------------- under_floor / clips --------------------
__global__ void finalize_kernel(const float* __restrict__ ahp0, const float* __restrict__ all0,
                                const float* __restrict__ around0, const float* __restrict__ mid0,
                                float* __restrict__ semacc, float* __restrict__ fpexp,
                                const float* __restrict__ posebuf,
                                float* __restrict__ out0) {
#pragma clang fp contract(off)
  int tid = blockIdx.x*256 + threadIdx.x;
  if (tid < 80000) {
    int b = tid / 10000;
    int yx = tid - b*10000;
    int y = yx / 100, x = yx - y*100;
    float u = (mid0[tid] == 0.0f) ? around0[tid] : 0.0f;
    if (y == 28 && x >= 47 && x < 53) {
      if (posebuf[b*8+4] != 0.0f) u = 1.0f;
    }
    float fm = ahp0[tid] + u;
    out0[tid] = fminf(fmaxf(fm, 0.0f), 1.0f);
    fpexp[tid] = fminf(fmaxf(all0[tid], 0.0f), 1.0f);
  } else if (tid < 80000 + 1280000) {
    int i = tid - 80000;
    float v = semacc[i] / 5.0f;
    semacc[i] = fminf(fmaxf(v, 0.0f), 1.0f);
  }
}

// -------------------- rotation resample (cropped support) --------------------
__device__ __forceinline__ float fetch_av(const float* __restrict__ out0,
                                          const float* __restrict__ fpexp,
                                          const float* __restrict__ semacc,
                                          int b, int cidx, float xf, float yf) {
  if (!(xf >= 0.0f && xf <= 479.0f && yf >= 0.0f && yf <= 479.0f)) return 0.0f;
  int xi = (int)xf, yi = (int)yf;
  int wx = xi - 190, wy = yi - 240;
  if (wx < 0 || wx >= 100 || wy < 0 || wy >= 100) return 0.0f;
  int o = b*10000 + wy*100 + wx;
  if (cidx == 0) return out0[o];
  if (cidx == 1) return fpexp[o];
  return semacc[(size_t)(b*NSEMC + (cidx-2))*10000 + wy*100 + wx];
}

__global__ void rotate_kernel(const float* __restrict__ out0, const float* __restrict__ fpexp,
                              const float* __restrict__ semacc,
                              const float* __restrict__ posebuf,
                              float* __restrict__ rot) {
#pragma clang fp contract(off)
  int tid = blockIdx.x*256 + threadIdx.x;
  if (tid >= BS*NROTC*CROPN*CROPN) return;
  int cj = tid % CROPN;
  int t1 = tid / CROPN;
  int ci = t1 % CROPN;
  int t2 = t1 / CROPN;
  int cidx = t2 % NROTC;
  int b = t2 / NROTC;
  int i = ci + CROP0, j = cj + CROP0;
  float X = (2.0f*(float)j + 1.0f)/480.0f - 1.0f;
  float Y = (2.0f*(float)i + 1.0f)/480.0f - 1.0f;
  const float* pb = posebuf + b*8;
  float gx = pb[0]*X - pb[1]*Y;
  float gy = pb[1]*X + pb[0]*Y;
  float x = (gx + 1.0f)*0.5f*479.0f;
  float y = (gy + 1.0f)*0.5f*479.0f;
  float x0 = floorf(x), y0 = floorf(y);
  float wx1 = x - x0, wx0 = 1.0f - wx1;
  float wy1 = y - y0, wy0 = 1.0f - wy1;
  float v00 = fetch_av(out0,fpexp,semacc,b,cidx,x0,       y0);
  float v10 = fetch_av(out0,fpexp,semacc,b,cidx,x0+1.0f,  y0);
  float v01 = fetch_av(out0,fpexp,semacc,b,cidx,x0,       y0+1.0f);
  float v11 = fetch_av(out0,fpexp,semacc,b,cidx,x0+1.0f,  y0+1.0f);
  float val = v00*(wx0*wy0) + v10*(wx1*wy0) + v01*(wx0*wy1) + v11*(wx1*wy1);
  rot[tid] = val;
}

// -------------------- translate + max + output --------------------
__device__ __forceinline__ float fetch_rot(const float* __restrict__ rot,
                                           int b, int cidx, float xf, float yf) {
  if (!(xf >= 0.0f && xf <= 479.0f && yf >= 0.0f && yf <= 479.0f)) return 0.0f;
  int xi = (int)xf, yi = (int)yf;
  int rx = xi - CROP0, ry = yi - CROP0;
  if (rx < 0 || rx >= CROPN || ry < 0 || ry >= CROPN) return 0.0f;
  return rot[((size_t)(b*NROTC + cidx)*CROPN + ry)*CROPN + rx];
}

__global__ void translate_kernel(const float* __restrict__ maps_last,
                                 const float* __restrict__ rot,
                                 const float* __restrict__ posebuf,
                                 float* __restrict__ out1) {
#pragma clang fp contract(off)
  size_t tid = (size_t)blockIdx.x*256 + threadIdx.x;
  if (tid >= (size_t)BS*CCH*480*480) return;
  int j = (int)(tid % 480);
  size_t t1 = tid / 480;
  int i = (int)(t1 % 480);
  size_t t2 = t1 / 480;
  int c = (int)(t2 % CCH);
  int b = (int)(t2 / CCH);
  float ml = maps_last[tid];
  if (c == 2 || c == 3) { out1[tid] = ml; return; }
  int cidx = (c < 2) ? c : c - 2;
  const float* pb = posebuf + b*8;
  float X = (2.0f*(float)j + 1.0f)/480.0f - 1.0f;
  float Y = (2.0f*(float)i + 1.0f)/480.0f - 1.0f;
  float gx = X + pb[2];
  float gy = Y + pb[3];
  float x = (gx + 1.0f)*0.5f*479.0f;
  float y = (gy + 1.0f)*0.5f*479.0f;
  float x0 = floorf(x), y0 = floorf(y);
  float wx1 = x - x0, wx0 = 1.0f - wx1;
  float wy1 = y - y0, wy0 = 1.0f - wy1;
  float v00 = fetch_rot(rot,b,cidx,x0,      y0);
  float v10 = fetch_rot(rot,b,cidx,x0+1.0f, y0);
  float v01 = fetch_rot(rot,b,cidx,x0,      y0+1.0f);
  float v11 = fetch_rot(rot,b,cidx,x0+1.0f, y0+1.0f);
  float val = v00*(wx0*wy0) + v10*(wx1*wy0) + v01*(wx0*wy1) + v11*(wx1*wy1);
  out1[tid] = fmaxf(ml, val);
}

extern "C" void kernel_launch(void* const* d_in, const int* in_sizes, int n_in,
                              void* d_out, int out_size, void* d_ws, size_t ws_size,
                              hipStream_t stream) {
  const float* obs        = (const float*)d_in[0];
  const float* pose_obs   = (const float*)d_in[1];
  const float* maps_last  = (const float*)d_in[2];
  const float* poses_last = (const float*)d_in[3];
  const float* agent_h    = (const float*)d_in[4];
  float* out = (float*)d_out;
  float* ws  = (float*)d_ws;

  // identical footprint to round 0 (proven to fit)
  const size_t WS_NEED = (size_t)64 + 80000ull*5 + 1280000ull + 7040000ull + 12800000ull;
  if (ws_size < WS_NEED*sizeof(float)) return;

  double focal_d = 640.0/2.0/tan(79.0/2.0*M_PI/180.0);
  float FOCALF = (float)focal_d;
  double vfov = atan(480.0/2.0/focal_d);
  float MINVF = (float)((0.88*100.0)/tan(vfov));

  float* posebuf = ws;                       // 64
  float* ahp0    = ws + 64;                  // 80000
  float* all0    = ahp0 + 80000;             // 80000
  float* around0 = all0 + 80000;             // 80000
  float* mid0    = around0 + 80000;          // 80000
  float* fpexp   = mid0 + 80000;             // 80000
  float* semacc  = fpexp + 80000;            // 1,280,000
  float* S0t     = semacc + 1280000;         // 7,040,000   [z][y][x][8]
  float* Ssemt   = S0t + 7040000;            // 12,800,000  [10][cell][8][16]
  float* rot     = S0t;                      // reuse after folds (7,750,656 fits)

  float* out0  = out;                        // fp_map_pred (8,1,100,100)
  float* out1  = out + 80000;                // map_pred (8,20,480,480)
  float* outp1 = out1 + (size_t)BS*CCH*480*480;
  float* outp2 = outp1 + 24;

  // zero projection accumulators + corner grids (folds re-zero the grids each batch)
  hipMemsetAsync(ahp0, 0,
                 ((size_t)80000*5 + 1280000ull + 7040000ull + 12800000ull)*sizeof(float),
                 stream);
  pose_kernel<<<1, 64, 0, stream>>>(pose_obs, poses_last, outp1, outp2, posebuf);
  mask_kernel<<<BS, 256, 0, stream>>>(obs, posebuf, MINVF);
  for (int b = 0; b < BS; b++) {
    scatter2_kernel<<<1200, 256, 0, stream>>>(obs, agent_h, S0t, Ssemt, FOCALF, b);
    fold2_kernel<<<3829, 256, 0, stream>>>(S0t, Ssemt, ahp0, all0, around0, mid0,
                                           semacc, b);
  }
  finalize_kernel<<<5313, 256, 0, stream>>>(ahp0, all0, around0, mid0, semacc,
                                            fpexp, posebuf, out0);
  rotate_kernel<<<30276, 256, 0, stream>>>(out0, fpexp, semacc, posebuf, rot);
  translate_kernel<<<144000, 256, 0, stream>>>(maps_last, rot, posebuf, out1);
}

// Round 3
// 1154.385 us; speedup vs baseline: 4.3170x; 4.3170x over previous
//
#include <hip/hip_runtime.h>
#include <math.h>

#define BS 8
#define CCH 20
#define IMH 480
#define IMW 640
#define HW (IMH*IMW)
#define VRX 100
#define NZ 88
#define NSEMC 16
#define CROP0 124
#define CROPN 232
#define NROTC 18
#define NBINS 880000         // 8 * 100 * 100 * 11 octants
#define SCAN_BLOCKS 860      // 860*1024 >= NBINS

// -------------------- pose / theta params --------------------
__global__ void pose_kernel(const float* __restrict__ pose_obs,
                            const float* __restrict__ poses_last,
                            float* __restrict__ outp1, float* __restrict__ outp2,
                            float* __restrict__ posebuf) {
#pragma clang fp contract(off)
  int b = threadIdx.x;
  if (b >= BS) return;
  const float DEGF = (float)57.29577951308232;
  float th = poses_last[b*3+2] / DEGF;
  float sn = sinf(th), cs = cosf(th);
  float ny = poses_last[b*3+1] + pose_obs[b*3+0]*sn + pose_obs[b*3+1]*cs;
  float nx = poses_last[b*3+0] + pose_obs[b*3+0]*cs - pose_obs[b*3+1]*sn;
  float nt = poses_last[b*3+2] + pose_obs[b*3+2]*DEGF;
  nt = fmodf(nt - 180.0f, 360.0f) + 180.0f;
  nt = fmodf(nt + 180.0f, 360.0f) - 180.0f;
  outp1[b*3+0] = nx; outp1[b*3+1] = ny; outp1[b*3+2] = nt;
  outp2[b*3+0] = nx; outp2[b*3+1] = ny; outp2[b*3+2] = nt;
  float t = (90.0f - nt) * (float)M_PI / 180.0f;
  float* pb = posebuf + b*8;
  pb[0] = cosf(t);
  pb[1] = sinf(t);
  pb[2] = -((nx*100.0f/5.0f - 240.0f)/240.0f);   // stx
  pb[3] = -((ny*100.0f/5.0f - 240.0f)/240.0f);   // sty
}

// -------------------- bottom-row depth mask --------------------
__global__ void mask_kernel(const float* __restrict__ obs, float* __restrict__ posebuf,
                            float MINVF) {
#pragma clang fp contract(off)
  int b = blockIdx.x;
  int t = threadIdx.x;
  const float* row = obs + (size_t)b*CCH*HW + 3*(size_t)HW + 479*IMW;
  int cnt = 0;
  for (int col = t; col < IMW; col += 256) {
    float d = row[col];
    float re = (d < 3000.0f) ? d : MINVF;
    float v = re - MINVF;
    v = v - 60.0f;
    if (v > 0.0f) cnt++;
  }
  __shared__ int sh[256];
  sh[t] = cnt;
  __syncthreads();
  for (int s = 128; s > 0; s >>= 1) {
    if (t < s) sh[t] += sh[t + s];
    __syncthreads();
  }
  if (t == 0) posebuf[b*8+4] = (sh[0] > 160) ? 1.0f : 0.0f;
}

// -------------------- shared transform (exact reference f32 sequence) --------------------
__device__ __forceinline__ void transform_pix(int r, int col, float Yd, float ah100,
                                              float FOCALF,
                                              float& pos0, float& pos1, float& pos2) {
#pragma clang fp contract(off)
  float X = ((float)col - 319.5f) * Yd / FOCALF;
  X = X + 250.0f;
  float Z = ((float)(479 - r) - 239.5f) * Yd / FOCALF;
  Z = Z + ah100;
  float Xc = (X/5.0f - 50.0f)/100.0f*2.0f;
  float Yc = (Yd/5.0f - 50.0f)/100.0f*2.0f;
  float Zc = (Z/5.0f - 28.0f)/88.0f*2.0f;
  pos0 = Xc*50.0f + 50.0f;
  pos1 = Yc*50.0f + 50.0f;
  pos2 = Zc*44.0f + 44.0f;
}

__device__ __forceinline__ int bin_key(int b, float pos0, float pos1, float pos2) {
  float f0 = floorf(pos0), f1 = floorf(pos1), f2 = floorf(pos2);
  if (!(f0 >= 0.0f && f0 <= 99.0f && f1 >= 0.0f && f1 <= 99.0f &&
        f2 >= 0.0f && f2 <= 87.0f)) return -1;
  int xi = (int)f0, yi = (int)f1, zi = (int)f2;
  return ((b*100 + yi)*100 + xi)*11 + (zi >> 3);
}

// -------------------- pass T: histogram --------------------
__global__ void bin_count_kernel(const float* __restrict__ obs,
                                 const float* __restrict__ agent_h,
                                 unsigned* __restrict__ cnt, float FOCALF) {
#pragma clang fp contract(off)
  int tid = blockIdx.x*256 + threadIdx.x;
  if (tid >= BS*HW) return;
  int b = tid / HW;
  int pix = tid - b*HW;
  int r = pix / IMW, col = pix - r*IMW;
  float Yd = obs[(size_t)b*CCH*HW + 3*(size_t)HW + pix];
  float ah100 = agent_h[b]*100.0f;
  float pos0, pos1, pos2;
  transform_pix(r, col, Yd, ah100, FOCALF, pos0, pos1, pos2);
  int key = bin_key(b, pos0, pos1, pos2);
  if (key >= 0) atomicAdd(&cnt[key], 1u);
}

// -------------------- scan (3 kernels) --------------------
__global__ void scan1_kernel(const unsigned* __restrict__ cnt,
                             unsigned* __restrict__ offs, unsigned* __restrict__ bsum) {
  __shared__ unsigned sh[256];
  int blk = blockIdx.x, t = threadIdx.x;
  int base = blk*1024 + t*4;
  unsigned v[4];
  unsigned s = 0;
#pragma unroll
  for (int i = 0; i < 4; i++) {
    unsigned c = (base + i < NBINS) ? cnt[base + i] : 0u;
    v[i] = s; s += c;
  }
  sh[t] = s;
  __syncthreads();
  for (int off = 1; off < 256; off <<= 1) {
    unsigned add = (t >= off) ? sh[t - off] : 0u;
    __syncthreads();
    sh[t] += add;
    __syncthreads();
  }
  unsigned texcl = sh[t] - s;
#pragma unroll
  for (int i = 0; i < 4; i++)
    if (base + i < NBINS) offs[base + i] = texcl + v[i];
  if (t == 255) bsum[blk] = sh[255];
}

__global__ void scan2_kernel(unsigned* __restrict__ bsum) {
  __shared__ unsigned sh[1024];
  int t = threadIdx.x;
  unsigned v = (t < SCAN_BLOCKS) ? bsum[t] : 0u;
  sh[t] = v;
  __syncthreads();
  for (int off = 1; off < 1024; off <<= 1) {
    unsigned add = (t >= off) ? sh[t - off] : 0u;
    __syncthreads();
    sh[t] += add;
    __syncthreads();
  }
  if (t < SCAN_BLOCKS) bsum[t] = sh[t] - v;   // exclusive
}

__global__ void scan3_kernel(unsigned* __restrict__ offs, const unsigned* __restrict__ bsum,
                             unsigned* __restrict__ cursor) {
  int i = blockIdx.x*256 + threadIdx.x;
  if (i >= NBINS) return;
  unsigned o = offs[i] + bsum[i >> 10];
  offs[i] = o;
  cursor[i] = o;
}

// -------------------- pass P: placement --------------------
__global__ void place_kernel(const float* __restrict__ obs,
                             const float* __restrict__ agent_h,
                             unsigned* __restrict__ cursor,
                             float4* __restrict__ records, float FOCALF) {
#pragma clang fp contract(off)
  int tid = blockIdx.x*256 + threadIdx.x;
  if (tid >= BS*HW) return;
  int b = tid / HW;
  int pix = tid - b*HW;
  int r = pix / IMW, col = pix - r*IMW;
  float Yd = obs[(size_t)b*CCH*HW + 3*(size_t)HW + pix];
  float ah100 = agent_h[b]*100.0f;
  float pos0, pos1, pos2;
  transform_pix(r, col, Yd, ah100, FOCALF, pos0, pos1, pos2);
  int key = bin_key(b, pos0, pos1, pos2);
  if (key >= 0) {
    unsigned idx = atomicAdd(&cursor[key], 1u);
    float4 rec;
    rec.x = pos0; rec.y = pos1; rec.z = pos2; rec.w = __int_as_float(pix);
    records[idx] = rec;
  }
}

// -------------------- pass G: occupancy gather + projections (no atomics) --------------------
__global__ void __launch_bounds__(256) gatherS_kernel(
    const float4* __restrict__ records, const unsigned* __restrict__ offs,
    const unsigned* __restrict__ cursor,
    float* __restrict__ ahp0, float* __restrict__ all0,
    float* __restrict__ around0, float* __restrict__ mid0) {
#pragma clang fp contract(off)
  __shared__ float A[256*17];
  __shared__ float red[64][4][4];
  int t = threadIdx.x;
  int cellsub = t >> 2, nb = t & 3;
  int blk = blockIdx.x;
  int b = blk / 154, blkb = blk - b*154;
  int cellidx = blkb*64 + cellsub;
  bool active = (cellidx < 9801);
  int ty = 1, tx = 1;
  if (active) { ty = 1 + cellidx/99; tx = 1 + cellidx - (cellidx/99)*99; }
  float* As = &A[t*17];
#pragma unroll
  for (int i = 0; i < 16; i++) As[i] = 0.0f;
  float pall = 0.f, pahp = 0.f, par = 0.f, pmid = 0.f;
  if (active) {
    int xi = tx - 1 + (nb & 1);
    int yi = ty - 1 + (nb >> 1);
    float fix = (float)(tx - xi);
    float fiy = (float)(ty - yi);
    int colkey = ((b*100 + yi)*100 + xi)*11;
    for (int oct = 0; oct < 11; oct++) {
      unsigned s = offs[colkey + oct], e = cursor[colkey + oct];
      if (s == e) continue;
      for (unsigned ri = s; ri < e; ri++) {
        float4 rec = records[ri];
        float px = floorf(rec.x) + fix;
        float py = floorf(rec.y) + fiy;
        float wx = 1.0f - fabsf(rec.x - px);
        float wy = 1.0f - fabsf(rec.y - py);
        float wxy = wx*wy;
        float f2 = floorf(rec.z);
        int zi = (int)f2;
        int z8 = zi & 7;
        float wz0 = 1.0f - fabsf(rec.z - f2);
        float wz1 = 1.0f - fabsf(rec.z - (f2 + 1.0f));
        As[z8*2 + 0] += wxy*wz0;
        As[z8*2 + 1] += wxy*wz1;
      }
      int zbase = oct*8;
#pragma unroll
      for (int z8 = 0; z8 < 8; z8++) {
        float a0 = As[z8*2], a1 = As[z8*2 + 1];
        As[z8*2] = 0.0f; As[z8*2 + 1] = 0.0f;
        int tz0 = zbase + z8;
        if (a0 != 0.0f && tz0 >= 1) {
          float rv = rintf(a0);
          pall += rv;
          if (tz0 < 23) { par += rv; if (tz0 >= 9) pmid += rv; }
          else if (tz0 < 33) pahp += rv;
        }
        int tz1 = tz0 + 1;
        if (a1 != 0.0f && tz1 <= 87) {
          float rv = rintf(a1);
          pall += rv;
          if (tz1 < 23) { par += rv; if (tz1 >= 9) pmid += rv; }
          else if (tz1 < 33) pahp += rv;
        }
      }
    }
  }
  red[cellsub][nb][0] = pall;
  red[cellsub][nb][1] = pahp;
  red[cellsub][nb][2] = par;
  red[cellsub][nb][3] = pmid;
  __syncthreads();
  if (nb == 0 && active) {
    float vall = 0.f, vahp = 0.f, varo = 0.f, vmid = 0.f;
#pragma unroll
    for (int k = 0; k < 4; k++) {
      vall += red[cellsub][k][0];
      vahp += red[cellsub][k][1];
      varo += red[cellsub][k][2];
      vmid += red[cellsub][k][3];
    }
    int o = b*10000 + ty*100 + tx;
    all0[o] = vall; ahp0[o] = vahp; around0[o] = varo; mid0[o] = vmid;
  }
}

// -------------------- pass M: sem gather (no atomics) --------------------
__global__ void __launch_bounds__(256) gatherSem_kernel(
    const float4* __restrict__ records, const unsigned* __restrict__ offs,
    const unsigned* __restrict__ cursor,
    const float* __restrict__ obs, float* __restrict__ semacc) {
#pragma clang fp contract(off)
  __shared__ float ST[256*41];
  __shared__ float red[8][16][4];
  int t = threadIdx.x;
  int cg = t & 7, nb = (t >> 3) & 3, cellsub = t >> 5;
  int blk = blockIdx.x;
  int b = blk / 1226, blkb = blk - b*1226;
  int cellidx = blkb*8 + cellsub;
  bool active = (cellidx < 9801);
  int ty = 1, tx = 1;
  if (active) { ty = 1 + cellidx/99; tx = 1 + cellidx - (cellidx/99)*99; }
  float* S = &ST[t*41];
#pragma unroll
  for (int i = 0; i < 40; i++) S[i] = 0.0f;
  if (active) {
    int xi = tx - 1 + (nb & 1);
    int yi = ty - 1 + (nb >> 1);
    float fix = (float)(tx - xi);
    float fiy = (float)(ty - yi);
    int colkey = ((b*100 + yi)*100 + xi)*11;
    unsigned s = offs[colkey + 2], e = cursor[colkey + 4];  // octants 2..4: zi in [16,39]
    const float* chbase = obs + (size_t)b*CCH*HW + (size_t)(4 + cg*2)*HW;
    for (unsigned ri = s; ri < e; ri++) {
      float4 rec = records[ri];
      float f2 = floorf(rec.z);
      int zi = (int)f2;
      if (zi < 22 || zi > 32) continue;
      int pix = __float_as_int(rec.w);
      float v0 = chbase[pix];
      float v1 = chbase[(size_t)HW + pix];
      float px = floorf(rec.x) + fix;
      float py = floorf(rec.y) + fiy;
      float wx = 1.0f - fabsf(rec.x - px);
      float wy = 1.0f - fabsf(rec.y - py);
      float wxy = wx*wy;
      float wz0 = 1.0f - fabsf(rec.z - f2);
      float wz1 = 1.0f - fabsf(rec.z - (f2 + 1.0f));
      float w0 = wxy*wz0, w1 = wxy*wz1;
      if (zi >= 23) {             // iz=0, tz=zi in [23,32]
        int idx = (zi - 23)*4;
        S[idx + 0] += v0*w0;
        S[idx + 1] += v1*w0;
      }
      if (zi <= 31) {             // iz=1, tz=zi+1 in [23,32]
        int idx = (zi + 1 - 23)*4 + 2;
        S[idx + 0] += v0*w1;
        S[idx + 1] += v1*w1;
      }
    }
  }
  float tot0 = 0.f, tot1 = 0.f;
#pragma unroll
  for (int sidx = 0; sidx < 10; sidx++) {
    tot0 += rintf(S[sidx*4 + 0]) + rintf(S[sidx*4 + 2]);
    tot1 += rintf(S[sidx*4 + 1]) + rintf(S[sidx*4 + 3]);
  }
  red[cellsub][cg*2 + 0][nb] = tot0;
  red[cellsub][cg*2 + 1][nb] = tot1;
  __syncthreads();
  if (t < 128) {
    int cell = t >> 4, ch = t & 15;
    int ci = blkb*8 + cell;
    if (ci < 9801) {
      int tyw = 1 + ci/99, txw = 1 + ci - (ci/99)*99;
      float v = red[cell][ch][0] + red[cell][ch][1] + red[cell][ch][2] + red[cell][ch][3];
      semacc[((size_t)b*NSEMC + ch)*10000 + tyw*100 + txw] = v;
    }
  }
}

// -------------------- under_floor / clips --------------------
__global__ void finalize_kernel(const float* __restrict__ ahp0, const float* __restrict__ all0,
                                const float* __restrict__ around0, const float* __restrict__ mid0,
                                float* __restrict__ semacc, float* __restrict__ fpexp,
                                const float* __restrict__ posebuf,
                                float* __restrict__ out0) {
#pragma clang fp contract(off)
  int tid = blockIdx.x*256 + threadIdx.x;
  if (tid < 80000) {
    int b = tid / 10000;
    int yx = tid - b*10000;
    int y = yx / 100, x = yx - y*100;
    float u = (mid0[tid] == 0.0f) ? around0[tid] : 0.0f;
    if (y == 28 && x >= 47 && x < 53) {
      if (posebuf[b*8+4] != 0.0f) u = 1.0f;
    }
    float fm = ahp0[tid] + u;
    out0[tid] = fminf(fmaxf(fm, 0.0f), 1.0f);
    fpexp[tid] = fminf(fmaxf(all0[tid], 0.0f), 1.0f);
  } else if (tid < 80000 + 1280000) {
    int i = tid - 80000;
    float v = semacc[i] / 5.0f;
    semacc[i] = fminf(fmaxf(v, 0.0f), 1.0f);
  }
}

// -------------------- rotation resample (cropped support) --------------------
__device__ __forceinline__ float fetch_av(const float* __restrict__ out0,
                                          const float* __restrict__ fpexp,
                                          const float* __restrict__ semacc,
                                          int b, int cidx, float xf, float yf) {
  if (!(xf >= 0.0f && xf <= 479.0f && yf >= 0.0f && yf <= 479.0f)) return 0.0f;
  int xi = (int)xf, yi = (int)yf;
  int wx = xi - 190, wy = yi - 240;
  if (wx < 0 || wx >= 100 || wy < 0 || wy >= 100) return 0.0f;
  int o = b*10000 + wy*100 + wx;
  if (cidx == 0) return out0[o];
  if (cidx == 1) return fpexp[o];
  return semacc[(size_t)(b*NSEMC + (cidx-2))*10000 + wy*100 + wx];
}

__global__ void rotate_kernel(const float* __restrict__ out0, const float* __restrict__ fpexp,
                              const float* __restrict__ semacc,
                              const float* __restrict__ posebuf,
                              float* __restrict__ rot) {
#pragma clang fp contract(off)
  int tid = blockIdx.x*256 + threadIdx.x;
  if (tid >= BS*NROTC*CROPN*CROPN) return;
  int cj = tid % CROPN;
  int t1 = tid / CROPN;
  int ci = t1 % CROPN;
  int t2 = t1 / CROPN;
  int cidx = t2 % NROTC;
  int b = t2 / NROTC;
  int i = ci + CROP0, j = cj + CROP0;
  float X = (2.0f*(float)j + 1.0f)/480.0f - 1.0f;
  float Y = (2.0f*(float)i + 1.0f)/480.0f - 1.0f;
  const float* pb = posebuf + b*8;
  float gx = pb[0]*X - pb[1]*Y;
  float gy = pb[1]*X + pb[0]*Y;
  float x = (gx + 1.0f)*0.5f*479.0f;
  float y = (gy + 1.0f)*0.5f*479.0f;
  float x0 = floorf(x), y0 = floorf(y);
  float wx1 = x - x0, wx0 = 1.0f - wx1;
  float wy1 = y - y0, wy0 = 1.0f - wy1;
  float v00 = fetch_av(out0,fpexp,semacc,b,cidx,x0,       y0);
  float v10 = fetch_av(out0,fpexp,semacc,b,cidx,x0+1.0f,  y0);
  float v01 = fetch_av(out0,fpexp,semacc,b,cidx,x0,       y0+1.0f);
  float v11 = fetch_av(out0,fpexp,semacc,b,cidx,x0+1.0f,  y0+1.0f);
  float val = v00*(wx0*wy0) + v10*(wx1*wy0) + v01*(wx0*wy1) + v11*(wx1*wy1);
  rot[tid] = val;
}

// -------------------- translate + max + output --------------------
__device__ __forceinline__ float fetch_rot(const float* __restrict__ rot,
                                           int b, int cidx, float xf, float yf) {
  if (!(xf >= 0.0f && xf <= 479.0f && yf >= 0.0f && yf <= 479.0f)) return 0.0f;
  int xi = (int)xf, yi = (int)yf;
  int rx = xi - CROP0, ry = yi - CROP0;
  if (rx < 0 || rx >= CROPN || ry < 0 || ry >= CROPN) return 0.0f;
  return rot[((size_t)(b*NROTC + cidx)*CROPN + ry)*CROPN + rx];
}

__global__ void translate_kernel(const float* __restrict__ maps_last,
                                 const float* __restrict__ rot,
                                 const float* __restrict__ posebuf,
                                 float* __restrict__ out1) {
#pragma clang fp contract(off)
  size_t tid = (size_t)blockIdx.x*256 + threadIdx.x;
  if (tid >= (size_t)BS*CCH*480*480) return;
  int j = (int)(tid % 480);
  size_t t1 = tid / 480;
  int i = (int)(t1 % 480);
  size_t t2 = t1 / 480;
  int c = (int)(t2 % CCH);
  int b = (int)(t2 / CCH);
  float ml = maps_last[tid];
  if (c == 2 || c == 3) { out1[tid] = ml; return; }
  int cidx = (c < 2) ? c : c - 2;
  const float* pb = posebuf + b*8;
  float X = (2.0f*(float)j + 1.0f)/480.0f - 1.0f;
  float Y = (2.0f*(float)i + 1.0f)/480.0f - 1.0f;
  float gx = X + pb[2];
  float gy = Y + pb[3];
  float x = (gx + 1.0f)*0.5f*479.0f;
  float y = (gy + 1.0f)*0.5f*479.0f;
  float x0 = floorf(x), y0 = floorf(y);
  float wx1 = x - x0, wx0 = 1.0f - wx1;
  float wy1 = y - y0, wy0 = 1.0f - wy1;
  float v00 = fetch_rot(rot,b,cidx,x0,      y0);
  float v10 = fetch_rot(rot,b,cidx,x0+1.0f, y0);
  float v01 = fetch_rot(rot,b,cidx,x0,      y0+1.0f);
  float v11 = fetch_rot(rot,b,cidx,x0+1.0f, y0+1.0f);
  float val = v00*(wx0*wy0) + v10*(wx1*wy0) + v01*(wx0*wy1) + v11*(wx1*wy1);
  out1[tid] = fmaxf(ml, val);
}

extern "C" void kernel_launch(void* const* d_in, const int* in_sizes, int n_in,
                              void* d_out, int out_size, void* d_ws, size_t ws_size,
                              hipStream_t stream) {
  const float* obs        = (const float*)d_in[0];
  const float* pose_obs   = (const float*)d_in[1];
  const float* maps_last  = (const float*)d_in[2];
  const float* poses_last = (const float*)d_in[3];
  const float* agent_h    = (const float*)d_in[4];
  float* out = (float*)d_out;
  float* ws  = (float*)d_ws;

  // layout (floats):
  // posebuf 64 | ahp0 80000 | all0 80000 | around0 80000 | mid0 80000 |
  // fpexp 80000 | semacc 1280000 | cnt 880000 | offs 880000 | cursor 880000 |
  // bsum 1024 | records 9830400 (float4 x 2457600)   [rot overlays records]
  const size_t WS_NEED = (size_t)64 + 80000ull*5 + 1280000ull + 880000ull*3 + 1024ull
                       + 9830400ull;
  if (ws_size < WS_NEED*sizeof(float)) return;

  double focal_d = 640.0/2.0/tan(79.0/2.0*M_PI/180.0);
  float FOCALF = (float)focal_d;
  double vfov = atan(480.0/2.0/focal_d);
  float MINVF = (float)((0.88*100.0)/tan(vfov));

  float* posebuf = ws;
  float* ahp0    = ws + 64;
  float* all0    = ahp0 + 80000;
  float* around0 = all0 + 80000;
  float* mid0    = around0 + 80000;
  float* fpexp   = mid0 + 80000;
  float* semacc  = fpexp + 80000;
  unsigned* cnt    = (unsigned*)(semacc + 1280000);
  unsigned* offs   = cnt + 880000;
  unsigned* cursor = offs + 880000;
  unsigned* bsum   = cursor + 880000;
  float4* records  = (float4*)(bsum + 1024);
  float* rot       = (float*)records;     // reuse after gathers (7,750,656 <= 9,830,400)

  float* out0  = out;                                  // fp_map_pred (8,1,100,100)
  float* out1  = out + 80000;                          // map_pred (8,20,480,480)
  float* outp1 = out1 + (size_t)BS*CCH*480*480;
  float* outp2 = outp1 + 24;

  // zero: projection maps + fpexp + semacc (contiguous) and bin counters
  hipMemsetAsync(ahp0, 0, ((size_t)80000*5 + 1280000ull)*sizeof(float), stream);
  hipMemsetAsync(cnt, 0, 880000ull*sizeof(unsigned), stream);

  pose_kernel<<<1, 64, 0, stream>>>(pose_obs, poses_last, outp1, outp2, posebuf);
  mask_kernel<<<BS, 256, 0, stream>>>(obs, posebuf, MINVF);

  bin_count_kernel<<<9600, 256, 0, stream>>>(obs, agent_h, cnt, FOCALF);
  scan1_kernel<<<SCAN_BLOCKS, 256, 0, stream>>>(cnt, offs, bsum);
  scan2_kernel<<<1, 1024, 0, stream>>>(bsum);
  scan3_kernel<<<3438, 256, 0, stream>>>(offs, bsum, cursor);
  place_kernel<<<9600, 256, 0, stream>>>(obs, agent_h, cursor, records, FOCALF);

  gatherS_kernel<<<1232, 256, 0, stream>>>(records, offs, cursor,
                                           ahp0, all0, around0, mid0);
  gatherSem_kernel<<<9808, 256, 0, stream>>>(records, offs, cursor, obs, semacc);

  finalize_kernel<<<5313, 256, 0, stream>>>(ahp0, all0, around0, mid0, semacc,
                                            fpexp, posebuf, out0);
  rotate_kernel<<<30276, 256, 0, stream>>>(out0, fpexp, semacc, posebuf, rot);
  translate_kernel<<<144000, 256, 0, stream>>>(maps_last, rot, posebuf, out1);
}

// Round 4
// 895.307 us; speedup vs baseline: 5.5662x; 1.2894x over previous
//
#include <hip/hip_runtime.h>
#include <math.h>

#define BS 8
#define CCH 20
#define IMH 480
#define IMW 640
#define HW (IMH*IMW)
#define VRX 100
#define NZ 88
#define NSEMC 16
#define CROP0 124
#define CROPN 232
#define NROTC 18
#define NBINS 880000         // 8 * 100 * 100 * 11 octants
#define NBINS2 80000         // 8 * 100 * 100 columns (sem)
#define SEMCAP 890000u       // capacity of compact sem records (exp ~540K)

// -------------------- pose / theta params --------------------
__global__ void pose_kernel(const float* __restrict__ pose_obs,
                            const float* __restrict__ poses_last,
                            float* __restrict__ outp1, float* __restrict__ outp2,
                            float* __restrict__ posebuf) {
#pragma clang fp contract(off)
  int b = threadIdx.x;
  if (b >= BS) return;
  const float DEGF = (float)57.29577951308232;
  float th = poses_last[b*3+2] / DEGF;
  float sn = sinf(th), cs = cosf(th);
  float ny = poses_last[b*3+1] + pose_obs[b*3+0]*sn + pose_obs[b*3+1]*cs;
  float nx = poses_last[b*3+0] + pose_obs[b*3+0]*cs - pose_obs[b*3+1]*sn;
  float nt = poses_last[b*3+2] + pose_obs[b*3+2]*DEGF;
  nt = fmodf(nt - 180.0f, 360.0f) + 180.0f;
  nt = fmodf(nt + 180.0f, 360.0f) - 180.0f;
  outp1[b*3+0] = nx; outp1[b*3+1] = ny; outp1[b*3+2] = nt;
  outp2[b*3+0] = nx; outp2[b*3+1] = ny; outp2[b*3+2] = nt;
  float t = (90.0f - nt) * (float)M_PI / 180.0f;
  float* pb = posebuf + b*8;
  pb[0] = cosf(t);
  pb[1] = sinf(t);
  pb[2] = -((nx*100.0f/5.0f - 240.0f)/240.0f);   // stx
  pb[3] = -((ny*100.0f/5.0f - 240.0f)/240.0f);   // sty
}

// -------------------- bottom-row depth mask --------------------
__global__ void mask_kernel(const float* __restrict__ obs, float* __restrict__ posebuf,
                            float MINVF) {
#pragma clang fp contract(off)
  int b = blockIdx.x;
  int t = threadIdx.x;
  const float* row = obs + (size_t)b*CCH*HW + 3*(size_t)HW + 479*IMW;
  int cnt = 0;
  for (int col = t; col < IMW; col += 256) {
    float d = row[col];
    float re = (d < 3000.0f) ? d : MINVF;
    float v = re - MINVF;
    v = v - 60.0f;
    if (v > 0.0f) cnt++;
  }
  __shared__ int sh[256];
  sh[t] = cnt;
  __syncthreads();
  for (int s = 128; s > 0; s >>= 1) {
    if (t < s) sh[t] += sh[t + s];
    __syncthreads();
  }
  if (t == 0) posebuf[b*8+4] = (sh[0] > 160) ? 1.0f : 0.0f;
}

// -------------------- shared transform (exact reference f32 sequence) --------------------
__device__ __forceinline__ void transform_pix(int r, int col, float Yd, float ah100,
                                              float FOCALF,
                                              float& pos0, float& pos1, float& pos2) {
#pragma clang fp contract(off)
  float X = ((float)col - 319.5f) * Yd / FOCALF;
  X = X + 250.0f;
  float Z = ((float)(479 - r) - 239.5f) * Yd / FOCALF;
  Z = Z + ah100;
  float Xc = (X/5.0f - 50.0f)/100.0f*2.0f;
  float Yc = (Yd/5.0f - 50.0f)/100.0f*2.0f;
  float Zc = (Z/5.0f - 28.0f)/88.0f*2.0f;
  pos0 = Xc*50.0f + 50.0f;
  pos1 = Yc*50.0f + 50.0f;
  pos2 = Zc*44.0f + 44.0f;
}

__device__ __forceinline__ int bin_key(int b, float pos0, float pos1, float pos2) {
  float f0 = floorf(pos0), f1 = floorf(pos1), f2 = floorf(pos2);
  if (!(f0 >= 0.0f && f0 <= 99.0f && f1 >= 0.0f && f1 <= 99.0f &&
        f2 >= 0.0f && f2 <= 87.0f)) return -1;
  int xi = (int)f0, yi = (int)f1, zi = (int)f2;
  return ((b*100 + yi)*100 + xi)*11 + (zi >> 3);
}

// -------------------- pass T: histograms (octant bins + sem column bins) --------------------
__global__ void bin_count_kernel(const float* __restrict__ obs,
                                 const float* __restrict__ agent_h,
                                 unsigned* __restrict__ cnt, unsigned* __restrict__ cnt2,
                                 float FOCALF) {
#pragma clang fp contract(off)
  int tid = blockIdx.x*256 + threadIdx.x;
  if (tid >= BS*HW) return;
  int b = tid / HW;
  int pix = tid - b*HW;
  int r = pix / IMW, col = pix - r*IMW;
  float Yd = obs[(size_t)b*CCH*HW + 3*(size_t)HW + pix];
  float ah100 = agent_h[b]*100.0f;
  float pos0, pos1, pos2;
  transform_pix(r, col, Yd, ah100, FOCALF, pos0, pos1, pos2);
  int key = bin_key(b, pos0, pos1, pos2);
  if (key >= 0) {
    atomicAdd(&cnt[key], 1u);
    int zi = (int)floorf(pos2);
    if (zi >= 22 && zi <= 32) atomicAdd(&cnt2[key/11], 1u);
  }
}

// -------------------- generalized scan (3 kernels) --------------------
__global__ void scan1_kernel(const unsigned* __restrict__ cnt,
                             unsigned* __restrict__ offs, unsigned* __restrict__ bsum,
                             int n) {
  __shared__ unsigned sh[256];
  int blk = blockIdx.x, t = threadIdx.x;
  int base = blk*1024 + t*4;
  unsigned v[4];
  unsigned s = 0;
#pragma unroll
  for (int i = 0; i < 4; i++) {
    unsigned c = (base + i < n) ? cnt[base + i] : 0u;
    v[i] = s; s += c;
  }
  sh[t] = s;
  __syncthreads();
  for (int off = 1; off < 256; off <<= 1) {
    unsigned add = (t >= off) ? sh[t - off] : 0u;
    __syncthreads();
    sh[t] += add;
    __syncthreads();
  }
  unsigned texcl = sh[t] - s;
#pragma unroll
  for (int i = 0; i < 4; i++)
    if (base + i < n) offs[base + i] = texcl + v[i];
  if (t == 255) bsum[blk] = sh[255];
}

__global__ void scan2_kernel(unsigned* __restrict__ bsum, int nb) {
  __shared__ unsigned sh[1024];
  int t = threadIdx.x;
  unsigned v = (t < nb) ? bsum[t] : 0u;
  sh[t] = v;
  __syncthreads();
  for (int off = 1; off < 1024; off <<= 1) {
    unsigned add = (t >= off) ? sh[t - off] : 0u;
    __syncthreads();
    sh[t] += add;
    __syncthreads();
  }
  if (t < nb) bsum[t] = sh[t] - v;   // exclusive
}

__global__ void scan3_kernel(unsigned* __restrict__ offs, const unsigned* __restrict__ bsum,
                             unsigned* __restrict__ cursor, int n) {
  int i = blockIdx.x*256 + threadIdx.x;
  if (i >= n) return;
  unsigned o = offs[i] + bsum[i >> 10];
  offs[i] = o;
  cursor[i] = o;
}

// -------------------- pass P: placement (occupancy records) --------------------
__global__ void place_kernel(const float* __restrict__ obs,
                             const float* __restrict__ agent_h,
                             unsigned* __restrict__ cursor,
                             float4* __restrict__ records, float FOCALF) {
#pragma clang fp contract(off)
  int tid = blockIdx.x*256 + threadIdx.x;
  if (tid >= BS*HW) return;
  int b = tid / HW;
  int pix = tid - b*HW;
  int r = pix / IMW, col = pix - r*IMW;
  float Yd = obs[(size_t)b*CCH*HW + 3*(size_t)HW + pix];
  float ah100 = agent_h[b]*100.0f;
  float pos0, pos1, pos2;
  transform_pix(r, col, Yd, ah100, FOCALF, pos0, pos1, pos2);
  int key = bin_key(b, pos0, pos1, pos2);
  if (key >= 0) {
    unsigned idx = atomicAdd(&cursor[key], 1u);
    float4 rec;
    rec.x = pos0; rec.y = pos1; rec.z = pos2; rec.w = 0.0f;
    records[idx] = rec;
  }
}

// -------------------- pass G: occupancy gather + projections (no atomics) --------------------
__global__ void __launch_bounds__(256) gatherS_kernel(
    const float4* __restrict__ records, const unsigned* __restrict__ offs,
    const unsigned* __restrict__ cursor,
    float* __restrict__ ahp0, float* __restrict__ all0,
    float* __restrict__ around0, float* __restrict__ mid0) {
#pragma clang fp contract(off)
  __shared__ float A[256*17];
  __shared__ float red[64][4][4];
  int t = threadIdx.x;
  int cellsub = t >> 2, nb = t & 3;
  int blk = blockIdx.x;
  int b = blk / 154, blkb = blk - b*154;
  int cellidx = blkb*64 + cellsub;
  bool active = (cellidx < 9801);
  int ty = 1, tx = 1;
  if (active) { ty = 1 + cellidx/99; tx = 1 + cellidx - (cellidx/99)*99; }
  float* As = &A[t*17];
#pragma unroll
  for (int i = 0; i < 16; i++) As[i] = 0.0f;
  float pall = 0.f, pahp = 0.f, par = 0.f, pmid = 0.f;
  if (active) {
    int xi = tx - 1 + (nb & 1);
    int yi = ty - 1 + (nb >> 1);
    float fix = (float)(tx - xi);
    float fiy = (float)(ty - yi);
    int colkey = ((b*100 + yi)*100 + xi)*11;
    for (int oct = 0; oct < 11; oct++) {
      unsigned s = offs[colkey + oct], e = cursor[colkey + oct];
      if (s == e) continue;
      for (unsigned ri = s; ri < e; ri++) {
        float4 rec = records[ri];
        float px = floorf(rec.x) + fix;
        float py = floorf(rec.y) + fiy;
        float wx = 1.0f - fabsf(rec.x - px);
        float wy = 1.0f - fabsf(rec.y - py);
        float wxy = wx*wy;
        float f2 = floorf(rec.z);
        int zi = (int)f2;
        int z8 = zi & 7;
        float wz0 = 1.0f - fabsf(rec.z - f2);
        float wz1 = 1.0f - fabsf(rec.z - (f2 + 1.0f));
        As[z8*2 + 0] += wxy*wz0;
        As[z8*2 + 1] += wxy*wz1;
      }
      int zbase = oct*8;
#pragma unroll
      for (int z8 = 0; z8 < 8; z8++) {
        float a0 = As[z8*2], a1 = As[z8*2 + 1];
        As[z8*2] = 0.0f; As[z8*2 + 1] = 0.0f;
        int tz0 = zbase + z8;
        if (a0 != 0.0f && tz0 >= 1) {
          float rv = rintf(a0);
          pall += rv;
          if (tz0 < 23) { par += rv; if (tz0 >= 9) pmid += rv; }
          else if (tz0 < 33) pahp += rv;
        }
        int tz1 = tz0 + 1;
        if (a1 != 0.0f && tz1 <= 87) {
          float rv = rintf(a1);
          pall += rv;
          if (tz1 < 23) { par += rv; if (tz1 >= 9) pmid += rv; }
          else if (tz1 < 33) pahp += rv;
        }
      }
    }
  }
  red[cellsub][nb][0] = pall;
  red[cellsub][nb][1] = pahp;
  red[cellsub][nb][2] = par;
  red[cellsub][nb][3] = pmid;
  __syncthreads();
  if (nb == 0 && active) {
    float vall = 0.f, vahp = 0.f, varo = 0.f, vmid = 0.f;
#pragma unroll
    for (int k = 0; k < 4; k++) {
      vall += red[cellsub][k][0];
      vahp += red[cellsub][k][1];
      varo += red[cellsub][k][2];
      vmid += red[cellsub][k][3];
    }
    int o = b*10000 + ty*100 + tx;
    all0[o] = vall; ahp0[o] = vahp; around0[o] = varo; mid0[o] = vmid;
  }
}

// -------------------- pass S1: compact sem records (pos + 16 ch inline) --------------------
__global__ void semplace_kernel(const float* __restrict__ obs,
                                const float* __restrict__ agent_h,
                                unsigned* __restrict__ cursor2,
                                float* __restrict__ semrec, float FOCALF) {
#pragma clang fp contract(off)
  int tid = blockIdx.x*256 + threadIdx.x;
  if (tid >= BS*HW) return;
  int b = tid / HW;
  int pix = tid - b*HW;
  int r = pix / IMW, col = pix - r*IMW;
  const float* obsb = obs + (size_t)b*CCH*HW;
  float Yd = obsb[3*(size_t)HW + pix];
  float ah100 = agent_h[b]*100.0f;
  float pos0, pos1, pos2;
  transform_pix(r, col, Yd, ah100, FOCALF, pos0, pos1, pos2);
  float f0 = floorf(pos0), f1 = floorf(pos1), f2 = floorf(pos2);
  if (f0 >= 0.0f && f0 <= 99.0f && f1 >= 0.0f && f1 <= 99.0f &&
      f2 >= 22.0f && f2 <= 32.0f) {
    int colb = (b*100 + (int)f1)*100 + (int)f0;
    unsigned idx = atomicAdd(&cursor2[colb], 1u);
    if (idx < SEMCAP) {
      float* dp = semrec + (size_t)idx*19;
      dp[0] = pos0; dp[1] = pos1; dp[2] = pos2;
#pragma unroll
      for (int ch = 0; ch < NSEMC; ch++)
        dp[3 + ch] = obsb[(size_t)(4 + ch)*HW + pix];
    }
  }
}

// -------------------- pass S2: column-major sem gather, walked once --------------------
// 128 threads = 8 columns x 16 ch-lanes. Private LDS stripe per lane (stride 84,
// bank-conflict-free: 84*t mod 32 bijective over t mod 32). Fold rintf locally,
// scatter <=4 nonzero atomics per (column, ch) to semacc.
__global__ void __launch_bounds__(128) gatherSem3_kernel(
    const float* __restrict__ semrec, const unsigned* __restrict__ offs2,
    const unsigned* __restrict__ cursor2, float* __restrict__ semacc) {
#pragma clang fp contract(off)
  __shared__ float st[128*84];
  int t = threadIdx.x;
  int ch = t & 15;
  int blk = blockIdx.x;
  int b = blk / 1250, cb = blk - b*1250;
  int colb = b*10000 + cb*8 + (t >> 4);
  int cy = (colb/100) % 100, cx = colb % 100;
  float* S = &st[t*84];
#pragma unroll
  for (int i = 0; i < 80; i++) S[i] = 0.0f;
  unsigned s = offs2[colb], e = cursor2[colb];
  for (unsigned ri = s; ri < e; ri++) {
    const float* rp = semrec + (size_t)ri*19;
    float pos0 = rp[0], pos1 = rp[1], pos2 = rp[2];
    float chv = rp[3 + ch];
    float f0 = floorf(pos0), f1 = floorf(pos1), f2 = floorf(pos2);
    int zi = (int)f2;                       // in [22,32]
    float wx0 = 1.0f - fabsf(pos0 - f0);
    float wx1 = 1.0f - fabsf(pos0 - (f0 + 1.0f));
    float wy0 = 1.0f - fabsf(pos1 - f1);
    float wy1 = 1.0f - fabsf(pos1 - (f1 + 1.0f));
    float w00 = wx0*wy0;   // iy=0, ix=0
    float w01 = wx1*wy0;   // iy=0, ix=1
    float w10 = wx0*wy1;   // iy=1, ix=0
    float w11 = wx1*wy1;   // iy=1, ix=1
    float wza = 1.0f - fabsf(pos2 - f2);
    float wzb = 1.0f - fabsf(pos2 - (f2 + 1.0f));
#pragma unroll
    for (int iz = 0; iz < 2; iz++) {
      int tzr = zi + iz - 23;
      if (tzr < 0 || tzr > 9) continue;
      float wz = (iz == 0) ? wza : wzb;
      int base = tzr*8 + iz*4;
      S[base + 0] += chv*(w00*wz);
      S[base + 1] += chv*(w01*wz);
      S[base + 2] += chv*(w10*wz);
      S[base + 3] += chv*(w11*wz);
    }
  }
  // fold: rintf per corner slot, sum over tz & iz
  float s00 = 0.f, s01 = 0.f, s10 = 0.f, s11 = 0.f;
#pragma unroll
  for (int q = 0; q < 20; q++) {
    s00 += rintf(S[q*4 + 0]);
    s01 += rintf(S[q*4 + 1]);
    s10 += rintf(S[q*4 + 2]);
    s11 += rintf(S[q*4 + 3]);
  }
  float* sa = semacc + ((size_t)b*NSEMC + ch)*10000;
  bool vx0 = (cx >= 1), vx1 = (cx <= 98), vy0 = (cy >= 1), vy1 = (cy <= 98);
  if (vy0 && vx0 && s00 != 0.f) atomicAdd(&sa[cy*100 + cx],           s00);
  if (vy0 && vx1 && s01 != 0.f) atomicAdd(&sa[cy*100 + cx + 1],       s01);
  if (vy1 && vx0 && s10 != 0.f) atomicAdd(&sa[(cy + 1)*100 + cx],     s10);
  if (vy1 && vx1 && s11 != 0.f) atomicAdd(&sa[(cy + 1)*100 + cx + 1], s11);
}

// -------------------- under_floor / clips --------------------
__global__ void finalize_kernel(const float* __restrict__ ahp0, const float* __restrict__ all0,
                                const float* __restrict__ around0, const float* __restrict__ mid0,
                                float* __restrict__ semacc, float* __restrict__ fpexp,
                                const float* __restrict__ posebuf,
                                float* __restrict__ out0) {
#pragma clang fp contract(off)
  int tid = blockIdx.x*256 + threadIdx.x;
  if (tid < 80000) {
    int b = tid / 10000;
    int yx = tid - b*10000;
    int y = yx / 100, x = yx - y*100;
    float u = (mid0[tid] == 0.0f) ? around0[tid] : 0.0f;
    if (y == 28 && x >= 47 && x < 53) {
      if (posebuf[b*8+4] != 0.0f) u = 1.0f;
    }
    float fm = ahp0[tid] + u;
    out0[tid] = fminf(fmaxf(fm, 0.0f), 1.0f);
    fpexp[tid] = fminf(fmaxf(all0[tid], 0.0f), 1.0f);
  } else if (tid < 80000 + 1280000) {
    int i = tid - 80000;
    float v = semacc[i] / 5.0f;
    semacc[i] = fminf(fmaxf(v, 0.0f), 1.0f);
  }
}

// -------------------- rotation resample (cropped support) --------------------
__device__ __forceinline__ float fetch_av(const float* __restrict__ out0,
                                          const float* __restrict__ fpexp,
                                          const float* __restrict__ semacc,
                                          int b, int cidx, float xf, float yf) {
  if (!(xf >= 0.0f && xf <= 479.0f && yf >= 0.0f && yf <= 479.0f)) return 0.0f;
  int xi = (int)xf, yi = (int)yf;
  int wx = xi - 190, wy = yi - 240;
  if (wx < 0 || wx >= 100 || wy < 0 || wy >= 100) return 0.0f;
  int o = b*10000 + wy*100 + wx;
  if (cidx == 0) return out0[o];
  if (cidx == 1) return fpexp[o];
  return semacc[(size_t)(b*NSEMC + (cidx-2))*10000 + wy*100 + wx];
}

__global__ void rotate_kernel(const float* __restrict__ out0, const float* __restrict__ fpexp,
                              const float* __restrict__ semacc,
                              const float* __restrict__ posebuf,
                              float* __restrict__ rot) {
#pragma clang fp contract(off)
  int tid = blockIdx.x*256 + threadIdx.x;
  if (tid >= BS*NROTC*CROPN*CROPN) return;
  int cj = tid % CROPN;
  int t1 = tid / CROPN;
  int ci = t1 % CROPN;
  int t2 = t1 / CROPN;
  int cidx = t2 % NROTC;
  int b = t2 / NROTC;
  int i = ci + CROP0, j = cj + CROP0;
  float X = (2.0f*(float)j + 1.0f)/480.0f - 1.0f;
  float Y = (2.0f*(float)i + 1.0f)/480.0f - 1.0f;
  const float* pb = posebuf + b*8;
  float gx = pb[0]*X - pb[1]*Y;
  float gy = pb[1]*X + pb[0]*Y;
  float x = (gx + 1.0f)*0.5f*479.0f;
  float y = (gy + 1.0f)*0.5f*479.0f;
  float x0 = floorf(x), y0 = floorf(y);
  float wx1 = x - x0, wx0 = 1.0f - wx1;
  float wy1 = y - y0, wy0 = 1.0f - wy1;
  float v00 = fetch_av(out0,fpexp,semacc,b,cidx,x0,       y0);
  float v10 = fetch_av(out0,fpexp,semacc,b,cidx,x0+1.0f,  y0);
  float v01 = fetch_av(out0,fpexp,semacc,b,cidx,x0,       y0+1.0f);
  float v11 = fetch_av(out0,fpexp,semacc,b,cidx,x0+1.0f,  y0+1.0f);
  float val = v00*(wx0*wy0) + v10*(wx1*wy0) + v01*(wx0*wy1) + v11*(wx1*wy1);
  rot[tid] = val;
}

// -------------------- translate + max + output --------------------
__device__ __forceinline__ float fetch_rot(const float* __restrict__ rot,
                                           int b, int cidx, float xf, float yf) {
  if (!(xf >= 0.0f && xf <= 479.0f && yf >= 0.0f && yf <= 479.0f)) return 0.0f;
  int xi = (int)xf, yi = (int)yf;
  int rx = xi - CROP0, ry = yi - CROP0;
  if (rx < 0 || rx >= CROPN || ry < 0 || ry >= CROPN) return 0.0f;
  return rot[((size_t)(b*NROTC + cidx)*CROPN + ry)*CROPN + rx];
}

__global__ void translate_kernel(const float* __restrict__ maps_last,
                                 const float* __restrict__ rot,
                                 const float* __restrict__ posebuf,
                                 float* __restrict__ out1) {
#pragma clang fp contract(off)
  size_t tid = (size_t)blockIdx.x*256 + threadIdx.x;
  if (tid >= (size_t)BS*CCH*480*480) return;
  int j = (int)(tid % 480);
  size_t t1 = tid / 480;
  int i = (int)(t1 % 480);
  size_t t2 = t1 / 480;
  int c = (int)(t2 % CCH);
  int b = (int)(t2 / CCH);
  float ml = maps_last[tid];
  if (c == 2 || c == 3) { out1[tid] = ml; return; }
  int cidx = (c < 2) ? c : c - 2;
  const float* pb = posebuf + b*8;
  float X = (2.0f*(float)j + 1.0f)/480.0f - 1.0f;
  float Y = (2.0f*(float)i + 1.0f)/480.0f - 1.0f;
  float gx = X + pb[2];
  float gy = Y + pb[3];
  float x = (gx + 1.0f)*0.5f*479.0f;
  float y = (gy + 1.0f)*0.5f*479.0f;
  float x0 = floorf(x), y0 = floorf(y);
  float wx1 = x - x0, wx0 = 1.0f - wx1;
  float wy1 = y - y0, wy0 = 1.0f - wy1;
  float v00 = fetch_rot(rot,b,cidx,x0,      y0);
  float v10 = fetch_rot(rot,b,cidx,x0+1.0f, y0);
  float v01 = fetch_rot(rot,b,cidx,x0,      y0+1.0f);
  float v11 = fetch_rot(rot,b,cidx,x0+1.0f, y0+1.0f);
  float val = v00*(wx0*wy0) + v10*(wx1*wy0) + v01*(wx0*wy1) + v11*(wx1*wy1);
  out1[tid] = fmaxf(ml, val);
}

extern "C" void kernel_launch(void* const* d_in, const int* in_sizes, int n_in,
                              void* d_out, int out_size, void* d_ws, size_t ws_size,
                              hipStream_t stream) {
  const float* obs        = (const float*)d_in[0];
  const float* pose_obs   = (const float*)d_in[1];
  const float* maps_last  = (const float*)d_in[2];
  const float* poses_last = (const float*)d_in[3];
  const float* agent_h    = (const float*)d_in[4];
  float* out = (float*)d_out;
  float* ws  = (float*)d_ws;

  // floats: posebuf 64 | proj 5x80000 | semacc 1.28M | cnt 880K | cnt2 80K |
  // offs 880K | cursor 880K | bsum 1K | offs2 80K | cursor2 80K | bsum2 1K |
  // bigbuf 16.91M (records 9.83M -> semrec 19x890K; rot overlays after)
  const size_t WS_NEED = (size_t)64 + 400000ull + 1280000ull
                       + 880000ull + 80000ull + 880000ull + 880000ull + 1024ull
                       + 80000ull + 80000ull + 1024ull + 16910000ull;  // 21,472,112
  if (ws_size < WS_NEED*sizeof(float)) return;

  double focal_d = 640.0/2.0/tan(79.0/2.0*M_PI/180.0);
  float FOCALF = (float)focal_d;
  double vfov = atan(480.0/2.0/focal_d);
  float MINVF = (float)((0.88*100.0)/tan(vfov));

  float* posebuf = ws;
  float* ahp0    = ws + 64;
  float* all0    = ahp0 + 80000;
  float* around0 = all0 + 80000;
  float* mid0    = around0 + 80000;
  float* fpexp   = mid0 + 80000;
  float* semacc  = fpexp + 80000;
  unsigned* cnt     = (unsigned*)(semacc + 1280000);
  unsigned* cnt2    = cnt + 880000;
  unsigned* offs    = cnt2 + 80000;
  unsigned* cursor  = offs + 880000;
  unsigned* bsum    = cursor + 880000;
  unsigned* offs2   = bsum + 1024;
  unsigned* cursor2 = offs2 + 80000;
  unsigned* bsum2   = cursor2 + 80000;
  float* bigbuf  = (float*)(bsum2 + 1024);
  float4* records = (float4*)bigbuf;   // 2,457,600 x 16B
  float* semrec   = bigbuf;            // overwrites records after gatherS
  float* rot      = bigbuf;            // overlays after gatherSem3

  float* out0  = out;                                  // fp_map_pred (8,1,100,100)
  float* out1  = out + 80000;                          // map_pred (8,20,480,480)
  float* outp1 = out1 + (size_t)BS*CCH*480*480;
  float* outp2 = outp1 + 24;

  hipMemsetAsync(ahp0, 0, ((size_t)400000 + 1280000ull)*sizeof(float), stream);
  hipMemsetAsync(cnt, 0, ((size_t)880000 + 80000ull)*sizeof(unsigned), stream);

  pose_kernel<<<1, 64, 0, stream>>>(pose_obs, poses_last, outp1, outp2, posebuf);
  mask_kernel<<<BS, 256, 0, stream>>>(obs, posebuf, MINVF);

  bin_count_kernel<<<9600, 256, 0, stream>>>(obs, agent_h, cnt, cnt2, FOCALF);
  scan1_kernel<<<860, 256, 0, stream>>>(cnt, offs, bsum, NBINS);
  scan2_kernel<<<1, 1024, 0, stream>>>(bsum, 860);
  scan3_kernel<<<3438, 256, 0, stream>>>(offs, bsum, cursor, NBINS);
  scan1_kernel<<<79, 256, 0, stream>>>(cnt2, offs2, bsum2, NBINS2);
  scan2_kernel<<<1, 1024, 0, stream>>>(bsum2, 79);
  scan3_kernel<<<313, 256, 0, stream>>>(offs2, bsum2, cursor2, NBINS2);

  place_kernel<<<9600, 256, 0, stream>>>(obs, agent_h, cursor, records, FOCALF);
  gatherS_kernel<<<1232, 256, 0, stream>>>(records, offs, cursor,
                                           ahp0, all0, around0, mid0);

  // records dead; reuse region for compact sem records
  semplace_kernel<<<9600, 256, 0, stream>>>(obs, agent_h, cursor2, semrec, FOCALF);
  gatherSem3_kernel<<<10000, 128, 0, stream>>>(semrec, offs2, cursor2, semacc);

  finalize_kernel<<<5313, 256, 0, stream>>>(ahp0, all0, around0, mid0, semacc,
                                            fpexp, posebuf, out0);
  rotate_kernel<<<30276, 256, 0, stream>>>(out0, fpexp, semacc, posebuf, rot);
  translate_kernel<<<144000, 256, 0, stream>>>(maps_last, rot, posebuf, out1);
}

// Round 5
// 824.636 us; speedup vs baseline: 6.0433x; 1.0857x over previous
//
#include <hip/hip_runtime.h>
#include <math.h>

#pragma clang fp contract(off)

#define BS 8
#define CCH 20
#define IMH 480
#define IMW 640
#define HW (IMH*IMW)
#define VRX 100
#define NZ 88
#define NSEMC 16
#define CROP0 124
#define CROPN 232
#define NROTC 18
#define NBINS 880000         // 8 * 100 * 100 * 11 octants
#define NBINS2 80000         // 8 * 100 * 100 columns (sem)
#define SEMCAP 890000u       // capacity of compact sem records (exp ~540K)

// -------------------- pose + bottom-row depth mask (fused) --------------------
__global__ void posemask_kernel(const float* __restrict__ pose_obs,
                                const float* __restrict__ poses_last,
                                const float* __restrict__ obs,
                                float* __restrict__ outp1, float* __restrict__ outp2,
                                float* __restrict__ posebuf, float MINVF) {
#pragma clang fp contract(off)
  int b = blockIdx.x;
  int t = threadIdx.x;
  if (t == 0) {
    const float DEGF = (float)57.29577951308232;
    float th = poses_last[b*3+2] / DEGF;
    float sn = sinf(th), cs = cosf(th);
    float ny = poses_last[b*3+1] + pose_obs[b*3+0]*sn + pose_obs[b*3+1]*cs;
    float nx = poses_last[b*3+0] + pose_obs[b*3+0]*cs - pose_obs[b*3+1]*sn;
    float nt = poses_last[b*3+2] + pose_obs[b*3+2]*DEGF;
    nt = fmodf(nt - 180.0f, 360.0f) + 180.0f;
    nt = fmodf(nt + 180.0f, 360.0f) - 180.0f;
    outp1[b*3+0] = nx; outp1[b*3+1] = ny; outp1[b*3+2] = nt;
    outp2[b*3+0] = nx; outp2[b*3+1] = ny; outp2[b*3+2] = nt;
    float tt = (90.0f - nt) * (float)M_PI / 180.0f;
    float* pb = posebuf + b*8;
    pb[0] = cosf(tt);
    pb[1] = sinf(tt);
    pb[2] = -((nx*100.0f/5.0f - 240.0f)/240.0f);   // stx
    pb[3] = -((ny*100.0f/5.0f - 240.0f)/240.0f);   // sty
  }
  const float* row = obs + (size_t)b*CCH*HW + 3*(size_t)HW + 479*IMW;
  int cnt = 0;
  for (int col = t; col < IMW; col += 256) {
    float d = row[col];
    float re = (d < 3000.0f) ? d : MINVF;
    float v = re - MINVF;
    v = v - 60.0f;
    if (v > 0.0f) cnt++;
  }
  __shared__ int sh[256];
  sh[t] = cnt;
  __syncthreads();
  for (int s = 128; s > 0; s >>= 1) {
    if (t < s) sh[t] += sh[t + s];
    __syncthreads();
  }
  if (t == 0) posebuf[b*8+4] = (sh[0] > 160) ? 1.0f : 0.0f;
}

// -------------------- shared transform (exact reference f32 sequence) --------------------
__device__ __forceinline__ void transform_pix(int r, int col, float Yd, float ah100,
                                              float FOCALF,
                                              float& pos0, float& pos1, float& pos2) {
#pragma clang fp contract(off)
  float X = ((float)col - 319.5f) * Yd / FOCALF;
  X = X + 250.0f;
  float Z = ((float)(479 - r) - 239.5f) * Yd / FOCALF;
  Z = Z + ah100;
  float Xc = (X/5.0f - 50.0f)/100.0f*2.0f;
  float Yc = (Yd/5.0f - 50.0f)/100.0f*2.0f;
  float Zc = (Z/5.0f - 28.0f)/88.0f*2.0f;
  pos0 = Xc*50.0f + 50.0f;
  pos1 = Yc*50.0f + 50.0f;
  pos2 = Zc*44.0f + 44.0f;
}

__device__ __forceinline__ int bin_key(int b, float pos0, float pos1, float pos2) {
  float f0 = floorf(pos0), f1 = floorf(pos1), f2 = floorf(pos2);
  if (!(f0 >= 0.0f && f0 <= 99.0f && f1 >= 0.0f && f1 <= 99.0f &&
        f2 >= 0.0f && f2 <= 87.0f)) return -1;
  int xi = (int)f0, yi = (int)f1, zi = (int)f2;
  return ((b*100 + yi)*100 + xi)*11 + (zi >> 3);
}

// -------------------- pass T: histograms (x4 pixels/thread for MLP) --------------------
__global__ void bin_count_kernel(const float* __restrict__ obs,
                                 const float* __restrict__ agent_h,
                                 unsigned* __restrict__ cnt, unsigned* __restrict__ cnt2,
                                 float FOCALF) {
#pragma clang fp contract(off)
  int tid = blockIdx.x*256 + threadIdx.x;
#pragma unroll
  for (int u = 0; u < 4; u++) {
    int p = tid + u*614400;
    int b = p / HW;
    int pix = p - b*HW;
    int r = pix / IMW, col = pix - r*IMW;
    float Yd = obs[(size_t)b*CCH*HW + 3*(size_t)HW + pix];
    float ah100 = agent_h[b]*100.0f;
    float pos0, pos1, pos2;
    transform_pix(r, col, Yd, ah100, FOCALF, pos0, pos1, pos2);
    int key = bin_key(b, pos0, pos1, pos2);
    if (key >= 0) {
      atomicAdd(&cnt[key], 1u);
      int zi = (int)floorf(pos2);
      if (zi >= 22 && zi <= 32) atomicAdd(&cnt2[key/11], 1u);
    }
  }
}

// -------------------- fused scans --------------------
__device__ __forceinline__ void scan1_body(const unsigned* __restrict__ cnt,
                                           unsigned* __restrict__ offs,
                                           unsigned* __restrict__ bsum,
                                           int n, int blk, unsigned* sh) {
  int t = threadIdx.x;
  int base = blk*1024 + t*4;
  unsigned v[4];
  unsigned s = 0;
#pragma unroll
  for (int i = 0; i < 4; i++) {
    unsigned c = (base + i < n) ? cnt[base + i] : 0u;
    v[i] = s; s += c;
  }
  sh[t] = s;
  __syncthreads();
  for (int off = 1; off < 256; off <<= 1) {
    unsigned add = (t >= off) ? sh[t - off] : 0u;
    __syncthreads();
    sh[t] += add;
    __syncthreads();
  }
  unsigned texcl = sh[t] - s;
#pragma unroll
  for (int i = 0; i < 4; i++)
    if (base + i < n) offs[base + i] = texcl + v[i];
  if (t == 255) bsum[blk] = sh[255];
}

__global__ void scan1m_kernel(const unsigned* __restrict__ cnt, unsigned* __restrict__ offs,
                              unsigned* __restrict__ bsum,
                              const unsigned* __restrict__ cnt2, unsigned* __restrict__ offs2,
                              unsigned* __restrict__ bsum2) {
  __shared__ unsigned sh[256];
  int blk = blockIdx.x;
  if (blk < 860) scan1_body(cnt, offs, bsum, NBINS, blk, sh);
  else           scan1_body(cnt2, offs2, bsum2, NBINS2, blk - 860, sh);
}

__global__ void scan2m_kernel(unsigned* __restrict__ bsum, unsigned* __restrict__ bsum2) {
  __shared__ unsigned sh[1024];
  unsigned* arr = (blockIdx.x == 0) ? bsum : bsum2;
  int nb = (blockIdx.x == 0) ? 860 : 79;
  int t = threadIdx.x;
  unsigned v = (t < nb) ? arr[t] : 0u;
  sh[t] = v;
  __syncthreads();
  for (int off = 1; off < 1024; off <<= 1) {
    unsigned add = (t >= off) ? sh[t - off] : 0u;
    __syncthreads();
    sh[t] += add;
    __syncthreads();
  }
  if (t < nb) arr[t] = sh[t] - v;   // exclusive
}

__global__ void scan3m_kernel(unsigned* __restrict__ offs, const unsigned* __restrict__ bsum,
                              unsigned* __restrict__ cursor,
                              unsigned* __restrict__ offs2, const unsigned* __restrict__ bsum2,
                              unsigned* __restrict__ cursor2) {
  int blk = blockIdx.x;
  if (blk < 3438) {
    int i = blk*256 + threadIdx.x;
    if (i >= NBINS) return;
    unsigned o = offs[i] + bsum[i >> 10];
    offs[i] = o;
    cursor[i] = o;
  } else {
    int i = (blk - 3438)*256 + threadIdx.x;
    if (i >= NBINS2) return;
    unsigned o = offs2[i] + bsum2[i >> 10];
    offs2[i] = o;
    cursor2[i] = o;
  }
}

// -------------------- pass P: placement (x2 pixels/thread) --------------------
__global__ void place_kernel(const float* __restrict__ obs,
                             const float* __restrict__ agent_h,
                             unsigned* __restrict__ cursor,
                             float4* __restrict__ records, float FOCALF) {
#pragma clang fp contract(off)
  int tid = blockIdx.x*256 + threadIdx.x;
#pragma unroll
  for (int u = 0; u < 2; u++) {
    int p = tid + u*1228800;
    int b = p / HW;
    int pix = p - b*HW;
    int r = pix / IMW, col = pix - r*IMW;
    float Yd = obs[(size_t)b*CCH*HW + 3*(size_t)HW + pix];
    float ah100 = agent_h[b]*100.0f;
    float pos0, pos1, pos2;
    transform_pix(r, col, Yd, ah100, FOCALF, pos0, pos1, pos2);
    int key = bin_key(b, pos0, pos1, pos2);
    if (key >= 0) {
      unsigned idx = atomicAdd(&cursor[key], 1u);
      float4 rec;
      rec.x = pos0; rec.y = pos1; rec.z = pos2; rec.w = 0.0f;
      records[idx] = rec;
    }
  }
}

// -------------------- pass G: column-major occupancy gather (records read ONCE) --------------------
// 256 threads = 32 columns x 8 corner-lanes (k = iy*4 + ix*2 + iz).
// Per lane: 8 z-slots in LDS (stride 9 for bank spread). Per octant: accumulate,
// then rintf-fold into projection registers. Output per column to colbuf (no atomics).
__global__ void __launch_bounds__(256) gatherS_cm_kernel(
    const float4* __restrict__ records, const unsigned* __restrict__ offs,
    const unsigned* __restrict__ cursor, float* __restrict__ colbuf) {
#pragma clang fp contract(off)
  __shared__ float S[256*9];
  __shared__ float red[32][8][4];
  int t = threadIdx.x;
  int k = t & 7, cw = t >> 3;
  int iz = k & 1, ix = (k >> 1) & 1, iy = (k >> 2) & 1;
  int col = blockIdx.x*32 + cw;
  int cx = col % 100, cy = (col/100) % 100;
  bool cellvalid = (cx+ix >= 1) && (cx+ix <= 99) && (cy+iy >= 1) && (cy+iy <= 99);
  float fx = (float)ix, fy = (float)iy, fz = (float)iz;
  float* Sl = &S[t*9];
#pragma unroll
  for (int i = 0; i < 8; i++) Sl[i] = 0.0f;
  float pall = 0.f, pahp = 0.f, par = 0.f, pmid = 0.f;
  int colkey = col*11;
  for (int oct = 0; oct < 11; oct++) {
    unsigned s = offs[colkey + oct], e = cursor[colkey + oct];
    for (unsigned ri = s; ri < e; ri++) {
      float4 rec = records[ri];          // same addr across 8 lanes -> broadcast
      float f0 = floorf(rec.x), f1 = floorf(rec.y), f2 = floorf(rec.z);
      float wx = 1.0f - fabsf(rec.x - (f0 + fx));
      float wy = 1.0f - fabsf(rec.y - (f1 + fy));
      float wz = 1.0f - fabsf(rec.z - (f2 + fz));
      float w = wx*wy;
      w = w*wz;
      int z8 = ((int)f2) & 7;
      Sl[z8] += w;
    }
    int zbase = oct*8;
#pragma unroll
    for (int z8 = 0; z8 < 8; z8++) {
      float a = Sl[z8];
      Sl[z8] = 0.0f;
      int tz = zbase + z8 + iz;
      if (a != 0.0f && tz >= 1 && tz <= 87) {
        float rv = rintf(a);
        pall += rv;
        if (tz < 23) { par += rv; if (tz >= 9) pmid += rv; }
        else if (tz < 33) pahp += rv;
      }
    }
  }
  if (!cellvalid) { pall = 0.f; pahp = 0.f; par = 0.f; pmid = 0.f; }
  red[cw][k][0] = pall;
  red[cw][k][1] = pahp;
  red[cw][k][2] = par;
  red[cw][k][3] = pmid;
  __syncthreads();
  // 32 cols x 4 cells x 4 proj = 512 outputs; pair-reduce iz
  for (int e2 = t; e2 < 512; e2 += 256) {
    int cw2 = e2 >> 4, rem = e2 & 15, c = rem >> 2, p = rem & 3;
    int colw = blockIdx.x*32 + cw2;
    colbuf[colw*16 + rem] = red[cw2][2*c][p] + red[cw2][2*c + 1][p];
  }
}

// -------------------- combine: per-cell sum of 4 base columns + finalize maps --------------------
__global__ void combine_kernel(const float* __restrict__ colbuf,
                               const float* __restrict__ posebuf,
                               float* __restrict__ out0, float* __restrict__ fpexp) {
#pragma clang fp contract(off)
  int tid = blockIdx.x*256 + threadIdx.x;
  if (tid >= 80000) return;
  int b = tid / 10000;
  int yx = tid - b*10000;
  int ty = yx / 100, tx = yx - (yx/100)*100;
  float all = 0.f, ahp = 0.f, ar = 0.f, mid = 0.f;
#pragma unroll
  for (int c = 0; c < 4; c++) {
    int iy = c >> 1, ix = c & 1;
    int cy = ty - iy, cx = tx - ix;
    if (cy < 0 || cx < 0) continue;
    const float* cb = &colbuf[((b*10000 + cy*100 + cx)*4 + c)*4];
    all += cb[0]; ahp += cb[1]; ar += cb[2]; mid += cb[3];
  }
  float u = (mid == 0.0f) ? ar : 0.0f;
  if (ty == 28 && tx >= 47 && tx < 53) {
    if (posebuf[b*8+4] != 0.0f) u = 1.0f;
  }
  float fm = ahp + u;
  out0[tid] = fminf(fmaxf(fm, 0.0f), 1.0f);
  fpexp[tid] = fminf(fmaxf(all, 0.0f), 1.0f);
}

// -------------------- pass S1: compact sem records (x2 pixels/thread) --------------------
__global__ void semplace_kernel(const float* __restrict__ obs,
                                const float* __restrict__ agent_h,
                                unsigned* __restrict__ cursor2,
                                float* __restrict__ semrec, float FOCALF) {
#pragma clang fp contract(off)
  int tid = blockIdx.x*256 + threadIdx.x;
#pragma unroll
  for (int u = 0; u < 2; u++) {
    int p = tid + u*1228800;
    int b = p / HW;
    int pix = p - b*HW;
    int r = pix / IMW, col = pix - r*IMW;
    const float* obsb = obs + (size_t)b*CCH*HW;
    float Yd = obsb[3*(size_t)HW + pix];
    float ah100 = agent_h[b]*100.0f;
    float pos0, pos1, pos2;
    transform_pix(r, col, Yd, ah100, FOCALF, pos0, pos1, pos2);
    float f0 = floorf(pos0), f1 = floorf(pos1), f2 = floorf(pos2);
    if (f0 >= 0.0f && f0 <= 99.0f && f1 >= 0.0f && f1 <= 99.0f &&
        f2 >= 22.0f && f2 <= 32.0f) {
      int colb = (b*100 + (int)f1)*100 + (int)f0;
      unsigned idx = atomicAdd(&cursor2[colb], 1u);
      if (idx < SEMCAP) {
        float* dp = semrec + (size_t)idx*19;
        dp[0] = pos0; dp[1] = pos1; dp[2] = pos2;
#pragma unroll
        for (int ch = 0; ch < NSEMC; ch++)
          dp[3 + ch] = obsb[(size_t)(4 + ch)*HW + pix];
      }
    }
  }
}

// -------------------- pass S2: column-major sem gather --------------------
__global__ void __launch_bounds__(128) gatherSem3_kernel(
    const float* __restrict__ semrec, const unsigned* __restrict__ offs2,
    const unsigned* __restrict__ cursor2, float* __restrict__ semacc) {
#pragma clang fp contract(off)
  __shared__ float st[128*84];
  int t = threadIdx.x;
  int ch = t & 15;
  int blk = blockIdx.x;
  int b = blk / 1250, cb = blk - b*1250;
  int colb = b*10000 + cb*8 + (t >> 4);
  int cy = (colb/100) % 100, cx = colb % 100;
  float* S = &st[t*84];
#pragma unroll
  for (int i = 0; i < 80; i++) S[i] = 0.0f;
  unsigned s = offs2[colb], e = cursor2[colb];
  for (unsigned ri = s; ri < e; ri++) {
    const float* rp = semrec + (size_t)ri*19;
    float pos0 = rp[0], pos1 = rp[1], pos2 = rp[2];
    float chv = rp[3 + ch];
    float f0 = floorf(pos0), f1 = floorf(pos1), f2 = floorf(pos2);
    int zi = (int)f2;                       // in [22,32]
    float wx0 = 1.0f - fabsf(pos0 - f0);
    float wx1 = 1.0f - fabsf(pos0 - (f0 + 1.0f));
    float wy0 = 1.0f - fabsf(pos1 - f1);
    float wy1 = 1.0f - fabsf(pos1 - (f1 + 1.0f));
    float w00 = wx0*wy0;
    float w01 = wx1*wy0;
    float w10 = wx0*wy1;
    float w11 = wx1*wy1;
    float wza = 1.0f - fabsf(pos2 - f2);
    float wzb = 1.0f - fabsf(pos2 - (f2 + 1.0f));
#pragma unroll
    for (int iz = 0; iz < 2; iz++) {
      int tzr = zi + iz - 23;
      if (tzr < 0 || tzr > 9) continue;
      float wz = (iz == 0) ? wza : wzb;
      int base = tzr*8 + iz*4;
      S[base + 0] += chv*(w00*wz);
      S[base + 1] += chv*(w01*wz);
      S[base + 2] += chv*(w10*wz);
      S[base + 3] += chv*(w11*wz);
    }
  }
  float s00 = 0.f, s01 = 0.f, s10 = 0.f, s11 = 0.f;
#pragma unroll
  for (int q = 0; q < 20; q++) {
    s00 += rintf(S[q*4 + 0]);
    s01 += rintf(S[q*4 + 1]);
    s10 += rintf(S[q*4 + 2]);
    s11 += rintf(S[q*4 + 3]);
  }
  float* sa = semacc + ((size_t)b*NSEMC + ch)*10000;
  bool vx0 = (cx >= 1), vx1 = (cx <= 98), vy0 = (cy >= 1), vy1 = (cy <= 98);
  if (vy0 && vx0 && s00 != 0.f) atomicAdd(&sa[cy*100 + cx],           s00);
  if (vy0 && vx1 && s01 != 0.f) atomicAdd(&sa[cy*100 + cx + 1],       s01);
  if (vy1 && vx0 && s10 != 0.f) atomicAdd(&sa[(cy + 1)*100 + cx],     s10);
  if (vy1 && vx1 && s11 != 0.f) atomicAdd(&sa[(cy + 1)*100 + cx + 1], s11);
}

// -------------------- rotation resample (cropped support; sem clip on read) --------------------
__device__ __forceinline__ float fetch_av(const float* __restrict__ out0,
                                          const float* __restrict__ fpexp,
                                          const float* __restrict__ semacc,
                                          int b, int cidx, float xf, float yf) {
  if (!(xf >= 0.0f && xf <= 479.0f && yf >= 0.0f && yf <= 479.0f)) return 0.0f;
  int xi = (int)xf, yi = (int)yf;
  int wx = xi - 190, wy = yi - 240;
  if (wx < 0 || wx >= 100 || wy < 0 || wy >= 100) return 0.0f;
  int o = b*10000 + wy*100 + wx;
  if (cidx == 0) return out0[o];
  if (cidx == 1) return fpexp[o];
  float v = semacc[(size_t)(b*NSEMC + (cidx-2))*10000 + wy*100 + wx] / 5.0f;
  return fminf(fmaxf(v, 0.0f), 1.0f);
}

__global__ void rotate_kernel(const float* __restrict__ out0, const float* __restrict__ fpexp,
                              const float* __restrict__ semacc,
                              const float* __restrict__ posebuf,
                              float* __restrict__ rot) {
#pragma clang fp contract(off)
  int tid = blockIdx.x*256 + threadIdx.x;
  if (tid >= BS*NROTC*CROPN*CROPN) return;
  int cj = tid % CROPN;
  int t1 = tid / CROPN;
  int ci = t1 % CROPN;
  int t2 = t1 / CROPN;
  int cidx = t2 % NROTC;
  int b = t2 / NROTC;
  int i = ci + CROP0, j = cj + CROP0;
  float X = (2.0f*(float)j + 1.0f)/480.0f - 1.0f;
  float Y = (2.0f*(float)i + 1.0f)/480.0f - 1.0f;
  const float* pb = posebuf + b*8;
  float gx = pb[0]*X - pb[1]*Y;
  float gy = pb[1]*X + pb[0]*Y;
  float x = (gx + 1.0f)*0.5f*479.0f;
  float y = (gy + 1.0f)*0.5f*479.0f;
  float x0 = floorf(x), y0 = floorf(y);
  float wx1 = x - x0, wx0 = 1.0f - wx1;
  float wy1 = y - y0, wy0 = 1.0f - wy1;
  float v00 = fetch_av(out0,fpexp,semacc,b,cidx,x0,       y0);
  float v10 = fetch_av(out0,fpexp,semacc,b,cidx,x0+1.0f,  y0);
  float v01 = fetch_av(out0,fpexp,semacc,b,cidx,x0,       y0+1.0f);
  float v11 = fetch_av(out0,fpexp,semacc,b,cidx,x0+1.0f,  y0+1.0f);
  float val = v00*(wx0*wy0) + v10*(wx1*wy0) + v01*(wx0*wy1) + v11*(wx1*wy1);
  rot[tid] = val;
}

// -------------------- translate + max + output --------------------
__device__ __forceinline__ float fetch_rot(const float* __restrict__ rot,
                                           int b, int cidx, float xf, float yf) {
  if (!(xf >= 0.0f && xf <= 479.0f && yf >= 0.0f && yf <= 479.0f)) return 0.0f;
  int xi = (int)xf, yi = (int)yf;
  int rx = xi - CROP0, ry = yi - CROP0;
  if (rx < 0 || rx >= CROPN || ry < 0 || ry >= CROPN) return 0.0f;
  return rot[((size_t)(b*NROTC + cidx)*CROPN + ry)*CROPN + rx];
}

__global__ void translate_kernel(const float* __restrict__ maps_last,
                                 const float* __restrict__ rot,
                                 const float* __restrict__ posebuf,
                                 float* __restrict__ out1) {
#pragma clang fp contract(off)
  size_t tid = (size_t)blockIdx.x*256 + threadIdx.x;
  if (tid >= (size_t)BS*CCH*480*480) return;
  int j = (int)(tid % 480);
  size_t t1 = tid / 480;
  int i = (int)(t1 % 480);
  size_t t2 = t1 / 480;
  int c = (int)(t2 % CCH);
  int b = (int)(t2 / CCH);
  float ml = maps_last[tid];
  if (c == 2 || c == 3) { out1[tid] = ml; return; }
  int cidx = (c < 2) ? c : c - 2;
  const float* pb = posebuf + b*8;
  float X = (2.0f*(float)j + 1.0f)/480.0f - 1.0f;
  float Y = (2.0f*(float)i + 1.0f)/480.0f - 1.0f;
  float gx = X + pb[2];
  float gy = Y + pb[3];
  float x = (gx + 1.0f)*0.5f*479.0f;
  float y = (gy + 1.0f)*0.5f*479.0f;
  float x0 = floorf(x), y0 = floorf(y);
  float wx1 = x - x0, wx0 = 1.0f - wx1;
  float wy1 = y - y0, wy0 = 1.0f - wy1;
  float v00 = fetch_rot(rot,b,cidx,x0,      y0);
  float v10 = fetch_rot(rot,b,cidx,x0+1.0f, y0);
  float v01 = fetch_rot(rot,b,cidx,x0,      y0+1.0f);
  float v11 = fetch_rot(rot,b,cidx,x0+1.0f, y0+1.0f);
  float val = v00*(wx0*wy0) + v10*(wx1*wy0) + v01*(wx0*wy1) + v11*(wx1*wy1);
  out1[tid] = fmaxf(ml, val);
}

extern "C" void kernel_launch(void* const* d_in, const int* in_sizes, int n_in,
                              void* d_out, int out_size, void* d_ws, size_t ws_size,
                              hipStream_t stream) {
  const float* obs        = (const float*)d_in[0];
  const float* pose_obs   = (const float*)d_in[1];
  const float* maps_last  = (const float*)d_in[2];
  const float* poses_last = (const float*)d_in[3];
  const float* agent_h    = (const float*)d_in[4];
  float* out = (float*)d_out;
  float* ws  = (float*)d_ws;

  // floats: posebuf 64 | fpexp 80K | semacc 1.28M | cnt 880K | cnt2 80K |
  // offs 880K | cursor 880K | bsum 1K | offs2 80K | cursor2 80K | bsum2 1K |
  // bigbuf 16.91M  (records 9.83M; colbuf overlays bigbuf+9.83M;
  //                 semrec 16.91M after combine; rot 7.75M after gatherSem3)
  const size_t WS_NEED = (size_t)64 + 80000ull + 1280000ull
                       + 880000ull + 80000ull + 880000ull + 880000ull + 1024ull
                       + 80000ull + 80000ull + 1024ull + 16910000ull;  // 21,152,112
  if (ws_size < WS_NEED*sizeof(float)) return;

  double focal_d = 640.0/2.0/tan(79.0/2.0*M_PI/180.0);
  float FOCALF = (float)focal_d;
  double vfov = atan(480.0/2.0/focal_d);
  float MINVF = (float)((0.88*100.0)/tan(vfov));

  float* posebuf = ws;
  float* fpexp   = ws + 64;
  float* semacc  = fpexp + 80000;
  unsigned* cnt     = (unsigned*)(semacc + 1280000);
  unsigned* cnt2    = cnt + 880000;
  unsigned* offs    = cnt2 + 80000;
  unsigned* cursor  = offs + 880000;
  unsigned* bsum    = cursor + 880000;
  unsigned* offs2   = bsum + 1024;
  unsigned* cursor2 = offs2 + 80000;
  unsigned* bsum2   = cursor2 + 80000;
  float* bigbuf  = (float*)(bsum2 + 1024);
  float4* records = (float4*)bigbuf;            // 2,457,600 x 16B
  float* colbuf   = bigbuf + 9830400;           // 1.28M floats (dead after combine)
  float* semrec   = bigbuf;                     // written after combine
  float* rot      = bigbuf;                     // after gatherSem3

  float* out0  = out;                                  // fp_map_pred (8,1,100,100)
  float* out1  = out + 80000;                          // map_pred (8,20,480,480)
  float* outp1 = out1 + (size_t)BS*CCH*480*480;
  float* outp2 = outp1 + 24;

  hipMemsetAsync(semacc, 0, 1280000ull*sizeof(float), stream);
  hipMemsetAsync(cnt, 0, ((size_t)880000 + 80000ull)*sizeof(unsigned), stream);

  posemask_kernel<<<BS, 256, 0, stream>>>(pose_obs, poses_last, obs,
                                          outp1, outp2, posebuf, MINVF);
  bin_count_kernel<<<2400, 256, 0, stream>>>(obs, agent_h, cnt, cnt2, FOCALF);
  scan1m_kernel<<<939, 256, 0, stream>>>(cnt, offs, bsum, cnt2, offs2, bsum2);
  scan2m_kernel<<<2, 1024, 0, stream>>>(bsum, bsum2);
  scan3m_kernel<<<3751, 256, 0, stream>>>(offs, bsum, cursor, offs2, bsum2, cursor2);

  place_kernel<<<4800, 256, 0, stream>>>(obs, agent_h, cursor, records, FOCALF);
  gatherS_cm_kernel<<<2500, 256, 0, stream>>>(records, offs, cursor, colbuf);
  combine_kernel<<<313, 256, 0, stream>>>(colbuf, posebuf, out0, fpexp);

  semplace_kernel<<<4800, 256, 0, stream>>>(obs, agent_h, cursor2, semrec, FOCALF);
  gatherSem3_kernel<<<10000, 128, 0, stream>>>(semrec, offs2, cursor2, semacc);

  rotate_kernel<<<30276, 256, 0, stream>>>(out0, fpexp, semacc, posebuf, rot);
  translate_kernel<<<144000, 256, 0, stream>>>(maps_last, rot, posebuf, out1);
}